// Round 1
// baseline (1266.232 us; speedup 1.0000x reference)
//
#include <hip/hip_runtime.h>
#include <hip/hip_bf16.h>
#include <cstdint>

// ---------------------------------------------------------------------------
// Meta-GCN LSTM encoder.  L=2, B=4, T=8, N=2048, C=2, H=64, K=3, M=32.
// DIN0=66, DIN1=128, DOUT=256.
//
// Plan:
//  prep:   G->bf16, init_h->XrecT (transposed bf16), x_seq->Xs0T, init_c->c
//  metaw:  all (t,b) meta-MLP weights -> B-fragment-swizzled bf16 W + f32 bias
//  S0x:    G @ x-part  (one small GEMM, all t)
//  loop t: GEMM1 rec (G @ h0_{t-1}) ; GEMM2+LSTM layer0 (writes h into XrecT0,
//          hs0T)
//  S1s:    G @ hs0 (one big batched GEMM, all t)
//  loop t: GEMM1 rec (G @ h1_{t-1}) ; GEMM2+LSTM layer1
// ---------------------------------------------------------------------------

typedef __hip_bfloat16 bf16;
typedef __attribute__((ext_vector_type(8))) short bf16x8;   // 8 bf16 in 4 VGPR
typedef __attribute__((ext_vector_type(4)))  float f32x4;
typedef __attribute__((ext_vector_type(16))) float f32x16;

// ---------------- workspace layout (bytes) ----------------
#define OFF_GBF    0u
#define OFF_XRT0   25165824u
#define OFF_XRT1   26214400u
#define OFF_XS0T   27262976u
#define OFF_HS0T   27787264u
#define OFF_S0X    36175872u
#define OFF_S1S    36962304u
#define OFF_REC    62128128u
#define OFF_W0SW   65273856u
#define OFF_W1SW   69992448u
#define OFF_BIAS0  76283904u
#define OFF_BIAS1  76316672u
#define OFF_C0     76349440u
#define OFF_C1     78446592u
#define WS_NEEDED  80543744u

// ---------------------------------------------------------------------------
// prep: grid-stride conversions.
//  G      : 3*2048*2048 = 12582912 f32 -> bf16 (same layout)
//  XrecT0 : [256 n][2048 j]  n=b*64+h  from init_h[0]
//  XrecT1 : same from init_h[1]
//  Xs0T   : [128 n][2048 j]  n=t*8+b*2+cc (rows 64..127 zero) from x_seq
//  c0,c1  : f32 copies of init_c
// ---------------------------------------------------------------------------
__global__ __launch_bounds__(256) void prep_kernel(
    const float* __restrict__ G, const float* __restrict__ x_seq,
    const float* __restrict__ init_h, const float* __restrict__ init_c,
    bf16* __restrict__ Gbf, bf16* __restrict__ XrT0, bf16* __restrict__ XrT1,
    bf16* __restrict__ Xs0T, float* __restrict__ c0, float* __restrict__ c1)
{
    const int SZ_G = 12582912, SZ_XR = 524288, SZ_XS = 262144, SZ_C = 524288;
    const int TOTAL = SZ_G + 2*SZ_XR + SZ_XS + 2*SZ_C;
    int stride = gridDim.x * 256;
    for (int idx = blockIdx.x*256 + threadIdx.x; idx < TOTAL; idx += stride) {
        int i0 = idx;
        if (i0 < SZ_G) { Gbf[i0] = __float2bfloat16(G[i0]); continue; }
        i0 -= SZ_G;
        if (i0 < SZ_XR) {
            int n = i0 >> 11, j = i0 & 2047; int b = n >> 6, h = n & 63;
            XrT0[i0] = __float2bfloat16(init_h[((size_t)b*2048 + j)*64 + h]);
            continue;
        }
        i0 -= SZ_XR;
        if (i0 < SZ_XR) {
            int n = i0 >> 11, j = i0 & 2047; int b = n >> 6, h = n & 63;
            XrT1[i0] = __float2bfloat16(init_h[((size_t)(4+b)*2048 + j)*64 + h]);
            continue;
        }
        i0 -= SZ_XR;
        if (i0 < SZ_XS) {
            int n = i0 >> 11, j = i0 & 2047;
            float v = 0.f;
            if (n < 64) {
                int t = n >> 3, rm = n & 7, b = rm >> 1, cc = rm & 1;
                v = x_seq[(((size_t)b*8 + t)*2048 + j)*2 + cc];
            }
            Xs0T[i0] = __float2bfloat16(v);
            continue;
        }
        i0 -= SZ_XS;
        if (i0 < SZ_C) { c0[i0] = init_c[i0]; continue; }
        i0 -= SZ_C;
        c1[i0] = init_c[SZ_C + i0];
    }
}

// ---------------------------------------------------------------------------
// metaw: per (t,b) meta-MLP.  hid = relu(meta@w1+b1) in LDS, then each thread
// owns one output column `o` (r is uniform = block id) and loops tb.
// W written in MFMA-B-fragment order: for fragment (rc,oc), lane l, elem e:
//   k_local = (l>>4)*8 + e  (r' = rc*32 + k_local),  n = oc*16 + (l&15).
// Layer0 row remap: orig r=k*66+d ->  r' = k*96 + (d<2 ? 64+d : d-2).
// ---------------------------------------------------------------------------
__global__ __launch_bounds__(256) void metaw_kernel(
    const float* __restrict__ x_meta,
    const float* __restrict__ lw1_0, const float* __restrict__ lb1_0,
    const float* __restrict__ lw2_0, const float* __restrict__ lb2_0,
    const float* __restrict__ bw1_0, const float* __restrict__ bb1_0,
    const float* __restrict__ bw2_0, const float* __restrict__ bb2_0,
    const float* __restrict__ lw1_1, const float* __restrict__ lb1_1,
    const float* __restrict__ lw2_1, const float* __restrict__ lb2_1,
    const float* __restrict__ bw1_1, const float* __restrict__ bb1_1,
    const float* __restrict__ bw2_1, const float* __restrict__ bb2_1,
    bf16* __restrict__ W0sw, bf16* __restrict__ W1sw,
    float* __restrict__ bias0, float* __restrict__ bias1)
{
    int tid = threadIdx.x, bid = blockIdx.x;
    const float *w1, *b1v, *w2, *b2v;
    int task, r = 0;
    if (bid < 384)      { task = 0; r = bid;       w1=lw1_1; b1v=lb1_1; w2=lw2_1; b2v=lb2_1; }
    else if (bid < 582) { task = 1; r = bid - 384; w1=lw1_0; b1v=lb1_0; w2=lw2_0; b2v=lb2_0; }
    else if (bid == 582){ task = 2;                w1=bw1_0; b1v=bb1_0; w2=bw2_0; b2v=bb2_0; }
    else                { task = 3;                w1=bw1_1; b1v=bb1_1; w2=bw2_1; b2v=bb2_1; }

    __shared__ float hid[32][64];
    for (int idx = tid; idx < 2048; idx += 256) {
        int tb = idx >> 6, h = idx & 63;
        int tt = tb >> 2, b = tb & 3;
        float a = b1v[h];
        #pragma unroll
        for (int m = 0; m < 32; m++)
            a += x_meta[((size_t)b*8 + tt)*32 + m] * w1[m*64 + h];
        hid[tb][h] = fmaxf(a, 0.f);
    }
    __syncthreads();

    int o = tid;
    int RO = (task == 0) ? 98304 : (task == 1) ? 50688 : 256;
    int ro = (task >= 2) ? o : (r*256 + o);
    float col[64];
    #pragma unroll
    for (int h = 0; h < 64; h++) col[h] = w2[(size_t)h*RO + ro];
    float base = b2v[ro];

    for (int tb = 0; tb < 32; tb++) {
        float v = base;
        #pragma unroll
        for (int h = 0; h < 64; h++) v += hid[tb][h]*col[h];
        if (task == 0) {
            int rp = r, rc = rp >> 5, rr = rp & 31;
            int oc = o >> 4, l = ((rr >> 3) << 4) + (o & 15), e = rr & 7;
            W1sw[(((size_t)tb*12 + rc)*16 + oc)*512 + l*8 + e] = __float2bfloat16(v);
        } else if (task == 1) {
            int k = r/66, d = r - k*66;
            int rp = k*96 + (d < 2 ? 64 + d : d - 2);
            int rc = rp >> 5, rr = rp & 31;
            int oc = o >> 4, l = ((rr >> 3) << 4) + (o & 15), e = rr & 7;
            W0sw[(((size_t)tb*9 + rc)*16 + oc)*512 + l*8 + e] = __float2bfloat16(v);
        } else if (task == 2) bias0[tb*256 + o] = v;
        else                  bias1[tb*256 + o] = v;
    }
}

// ---------------------------------------------------------------------------
// gemm_k: C[6144][ncols] = Gbf[6144][2048] @ BmT[ncols][2048]^T, bf16 out.
// No LDS: direct per-lane 16B global loads (G and BmT are L2/L3 resident),
// depth-2 register prefetch, v_mfma_f32_32x32x16_bf16.
// Block = 64 rows x 128 cols, 4 waves (2x2), wave tile 32x64.
// MODE 0: rec  [kk][i][256];  MODE 1: S1s [t][kk][i][256];  MODE 2: S0x [kk][i][64]
// XCD-bijective swizzle: both n-tiles of an m-panel land on one XCD.
// ---------------------------------------------------------------------------
#define B1_LOAD(F, KB)                                                         \
    do { _Pragma("unroll") for (int kc = 0; kc < 4; kc++) {                    \
        F##a[kc]  = *(const bf16x8*)(arow  + (KB) + kc*16);                    \
        F##b0[kc] = *(const bf16x8*)(brow0 + (KB) + kc*16);                    \
        F##b1[kc] = *(const bf16x8*)(brow1 + (KB) + kc*16); } } while (0)

#define B1_COMP(F)                                                             \
    do { _Pragma("unroll") for (int kc = 0; kc < 4; kc++) {                    \
        acc0 = __builtin_amdgcn_mfma_f32_32x32x16_bf16(F##a[kc], F##b0[kc], acc0, 0, 0, 0); \
        acc1 = __builtin_amdgcn_mfma_f32_32x32x16_bf16(F##a[kc], F##b1[kc], acc1, 0, 0, 0); } } while (0)

template<int MODE>
__global__ __launch_bounds__(256) void gemm_k(
    const short* __restrict__ A, const short* __restrict__ Bm,
    bf16* __restrict__ dst)
{
    int tid = threadIdx.x, lane = tid & 63, wid = tid >> 6;
    int wr = wid >> 1, wc = wid & 1;
    int bid = blockIdx.x;
    int x = bid & 7, j = bid >> 3;
    int mt = (j % 12) * 8 + x;        // m-panel (96 total)
    int nt = j / 12;                  // n-tile
    int kk = mt >> 5;                 // support index 0..2
    int ibase = (mt & 31) * 64;
    int l31 = lane & 31, lhi = lane >> 5;

    const short* arow  = A  + (size_t)(mt*64 + wr*32 + l31)*2048 + lhi*8;
    int n0 = nt*128 + wc*64;
    const short* brow0 = Bm + (size_t)(n0 + l31)*2048 + lhi*8;
    const short* brow1 = brow0 + (size_t)32*2048;

    f32x16 acc0, acc1;
    #pragma unroll
    for (int q = 0; q < 16; q++) { acc0[q] = 0.f; acc1[q] = 0.f; }

    bf16x8 f0a[4], f0b0[4], f0b1[4], f1a[4], f1b0[4], f1b1[4];
    B1_LOAD(f0, 0);
    B1_LOAD(f1, 64);
    #pragma unroll 1
    for (int kb = 0; kb < 2048 - 128; kb += 128) {
        B1_COMP(f0); B1_LOAD(f0, kb + 128);
        B1_COMP(f1); B1_LOAD(f1, kb + 192);
    }
    B1_COMP(f0); B1_COMP(f1);

    // store: D layout (32x32): col = lane&31, row = (reg&3)+8*(reg>>2)+4*(lane>>5)
    #pragma unroll
    for (int nf = 0; nf < 2; nf++) {
        const f32x16 ac = nf ? acc1 : acc0;
        int n = n0 + nf*32 + l31;
        size_t base; bool ok = true; int ld;
        if (MODE == 0) { base = (size_t)kk*2048*256 + n; ld = 256; }
        else if (MODE == 1) {
            int tt = n >> 8, c = n & 255;
            base = ((size_t)tt*3 + kk)*2048*256 + c; ld = 256;
        } else {
            if (n >= 64) ok = false;
            base = (size_t)kk*2048*64 + n; ld = 64;
        }
        if (ok) {
            #pragma unroll
            for (int reg = 0; reg < 16; reg++) {
                int irow = ibase + wr*32 + (reg & 3) + 8*(reg >> 2) + 4*lhi;
                dst[base + (size_t)irow*ld] = __float2bfloat16(ac[reg]);
            }
        }
    }
}

// ---------------------------------------------------------------------------
// gemm2_lstm: out[b][i][o] = sum_r sup[b][i][r'] * W[t][b][r'][o] + bias, then
// LSTM cell update.  Block = (b, 32-row tile), 4 waves; wave w owns gate
// columns o = g*64 + w*16 + (lane&15) for g=0..3 -> LSTM fully in-wave.
// A-frags (16x16x32): lane: i = i0 + (lane&15), r' = rc*32 + (lane>>4)*8+e,
// read straight from rec/static bf16 buffers (L2-hot).  W read as pre-swizzled
// contiguous fragments.  No LDS, no barriers.
// LAYER 0: NC=9  chunks: per k {rec h0..31, rec h32..63, special(x cols + pad)}
// LAYER 1: NC=12 chunks: per k {S1s 0..31, S1s 32..63, rec 0..31, rec 32..63}
// ---------------------------------------------------------------------------
template<int LAYER>
__global__ __launch_bounds__(256) void gemm2_lstm(
    const short* __restrict__ rec, const short* __restrict__ Sstat,
    const short* __restrict__ Wsw, const float* __restrict__ bias,
    float* __restrict__ cbuf, bf16* __restrict__ xrT, bf16* __restrict__ hs0T,
    float* __restrict__ out, int t)
{
    constexpr int NC = (LAYER == 0) ? 9 : 12;
    int tid = threadIdx.x, lane = tid & 63, w = tid >> 6;
    int b = blockIdx.x & 3, it = blockIdx.x >> 2;
    int tb = t*4 + b;
    int l15 = lane & 15, lg = lane >> 4;
    int iA0 = it*32 + l15;
    int iA1 = iA0 + 16;

    f32x4 acc[2][4];
    #pragma unroll
    for (int mi = 0; mi < 2; mi++)
        #pragma unroll
        for (int g = 0; g < 4; g++)
            #pragma unroll
            for (int q = 0; q < 4; q++) acc[mi][g][q] = 0.f;

    const short* WswT = Wsw + (size_t)tb*NC*16*512;

    #pragma unroll
    for (int rc = 0; rc < NC; rc++) {
        bf16x8 a0, a1;
        if (LAYER == 1) {
            int kkx = rc >> 2, d0 = (rc & 3)*32;
            const short* src = (d0 < 64) ? (Sstat + (size_t)t*3*2048*256) : rec;
            int col = b*64 + (d0 & 63) + lg*8;
            a0 = *(const bf16x8*)(src + ((size_t)kkx*2048 + iA0)*256 + col);
            a1 = *(const bf16x8*)(src + ((size_t)kkx*2048 + iA1)*256 + col);
        } else {
            int kkx = rc/3, dd = rc - kkx*3;
            if (dd < 2) {
                int col = b*64 + dd*32 + lg*8;
                a0 = *(const bf16x8*)(rec + ((size_t)kkx*2048 + iA0)*256 + col);
                a1 = *(const bf16x8*)(rec + ((size_t)kkx*2048 + iA1)*256 + col);
            } else {
                #pragma unroll
                for (int e = 0; e < 8; e++) { a0[e] = 0; a1[e] = 0; }
                if (lg == 0) {   // r'_local 64..65 = x static cols
                    unsigned v0 = *(const unsigned*)(Sstat + ((size_t)kkx*2048 + iA0)*64 + t*8 + b*2);
                    unsigned v1 = *(const unsigned*)(Sstat + ((size_t)kkx*2048 + iA1)*64 + t*8 + b*2);
                    a0[0] = (short)(v0 & 0xffff); a0[1] = (short)(v0 >> 16);
                    a1[0] = (short)(v1 & 0xffff); a1[1] = (short)(v1 >> 16);
                }
            }
        }
        #pragma unroll
        for (int g = 0; g < 4; g++) {
            bf16x8 wf = *(const bf16x8*)(WswT + (((size_t)rc*16 + (g*4 + w))*64 + lane)*8);
            acc[0][g] = __builtin_amdgcn_mfma_f32_16x16x32_bf16(a0, wf, acc[0][g], 0, 0, 0);
            acc[1][g] = __builtin_amdgcn_mfma_f32_16x16x32_bf16(a1, wf, acc[1][g], 0, 0, 0);
        }
    }

    // epilogue: D layout (16x16): col = lane&15, row = (lane>>4)*4 + reg
    int hcol = w*16 + l15;
    float bia[4];
    #pragma unroll
    for (int g = 0; g < 4; g++) bia[g] = bias[tb*256 + g*64 + hcol];

    #pragma unroll
    for (int mi = 0; mi < 2; mi++) {
        #pragma unroll
        for (int r = 0; r < 4; r++) {
            int i = it*32 + mi*16 + lg*4 + r;
            float gi = acc[mi][0][r] + bia[0];
            float gf = acc[mi][1][r] + bia[1];
            float go = acc[mi][2][r] + bia[2];
            float gg = acc[mi][3][r] + bia[3];
            size_t cidx = ((size_t)b*2048 + i)*64 + hcol;
            float c_old = cbuf[cidx];
            float si = 1.f/(1.f + __expf(-gi));
            float sf = 1.f/(1.f + __expf(-gf));
            float so = 1.f/(1.f + __expf(-go));
            float cn = sf*c_old + si*tanhf(gg);
            float hn = so*tanhf(cn);
            cbuf[cidx] = cn;
            bf16 hb = __float2bfloat16(hn);
            xrT[((size_t)b*64 + hcol)*2048 + i] = hb;
            if (LAYER == 0)
                hs0T[((size_t)t*256 + b*64 + hcol)*2048 + i] = hb;
            if (t == 7) {
                out[(((size_t)LAYER*4 + b)*2048 + i)*64 + hcol]       = hn; // h section
                out[(((size_t)(2 + LAYER)*4 + b)*2048 + i)*64 + hcol] = cn; // c section
            }
        }
    }
}

// ---------------------------------------------------------------------------
extern "C" void kernel_launch(void* const* d_in, const int* in_sizes, int n_in,
                              void* d_out, int out_size, void* d_ws, size_t ws_size,
                              hipStream_t stream)
{
    const float* G      = (const float*)d_in[0];
    const float* x_seq  = (const float*)d_in[1];
    const float* init_h = (const float*)d_in[2];
    const float* init_c = (const float*)d_in[3];
    const float* x_meta = (const float*)d_in[4];
    const float* lw1_0 = (const float*)d_in[5],  *lb1_0 = (const float*)d_in[6];
    const float* lw2_0 = (const float*)d_in[7],  *lb2_0 = (const float*)d_in[8];
    const float* bw1_0 = (const float*)d_in[9],  *bb1_0 = (const float*)d_in[10];
    const float* bw2_0 = (const float*)d_in[11], *bb2_0 = (const float*)d_in[12];
    const float* lw1_1 = (const float*)d_in[13], *lb1_1 = (const float*)d_in[14];
    const float* lw2_1 = (const float*)d_in[15], *lb2_1 = (const float*)d_in[16];
    const float* bw1_1 = (const float*)d_in[17], *bb1_1 = (const float*)d_in[18];
    const float* bw2_1 = (const float*)d_in[19], *bb2_1 = (const float*)d_in[20];

    if (ws_size < WS_NEEDED) return;   // workspace too small -> will fail validation loudly

    char* ws = (char*)d_ws;
    bf16*  Gbf   = (bf16*) (ws + OFF_GBF);
    bf16*  XrT0  = (bf16*) (ws + OFF_XRT0);
    bf16*  XrT1  = (bf16*) (ws + OFF_XRT1);
    bf16*  Xs0T  = (bf16*) (ws + OFF_XS0T);
    bf16*  hs0T  = (bf16*) (ws + OFF_HS0T);
    bf16*  S0x   = (bf16*) (ws + OFF_S0X);
    bf16*  S1s   = (bf16*) (ws + OFF_S1S);
    bf16*  rec   = (bf16*) (ws + OFF_REC);
    bf16*  W0sw  = (bf16*) (ws + OFF_W0SW);
    bf16*  W1sw  = (bf16*) (ws + OFF_W1SW);
    float* bias0 = (float*)(ws + OFF_BIAS0);
    float* bias1 = (float*)(ws + OFF_BIAS1);
    float* c0    = (float*)(ws + OFF_C0);
    float* c1    = (float*)(ws + OFF_C1);
    float* out   = (float*)d_out;

    prep_kernel<<<8192, 256, 0, stream>>>(G, x_seq, init_h, init_c,
                                          Gbf, XrT0, XrT1, Xs0T, c0, c1);
    metaw_kernel<<<584, 256, 0, stream>>>(x_meta,
        lw1_0, lb1_0, lw2_0, lb2_0, bw1_0, bb1_0, bw2_0, bb2_0,
        lw1_1, lb1_1, lw2_1, lb2_1, bw1_1, bb1_1, bw2_1, bb2_1,
        W0sw, W1sw, bias0, bias1);

    // static x-part for layer 0 (all t at once): N = 64 (padded B rows to 128)
    gemm_k<2><<<96, 256, 0, stream>>>((const short*)Gbf, (const short*)Xs0T, S0x);

    // layer 0 time loop
    for (int t = 0; t < 8; t++) {
        gemm_k<0><<<192, 256, 0, stream>>>((const short*)Gbf, (const short*)XrT0, rec);
        gemm2_lstm<0><<<256, 256, 0, stream>>>((const short*)rec, (const short*)S0x,
            (const short*)W0sw, bias0, c0, XrT0, hs0T, out, t);
    }

    // batched static hs0-part for layer 1 (all t at once): N = 2048
    gemm_k<1><<<1536, 256, 0, stream>>>((const short*)Gbf, (const short*)hs0T, S1s);

    // layer 1 time loop
    for (int t = 0; t < 8; t++) {
        gemm_k<0><<<192, 256, 0, stream>>>((const short*)Gbf, (const short*)XrT1, rec);
        gemm2_lstm<1><<<256, 256, 0, stream>>>((const short*)rec, (const short*)S1s,
            (const short*)W1sw, bias1, c1, XrT1, nullptr, out, t);
    }
}

// Round 2
// 756.050 us; speedup vs baseline: 1.6748x; 1.6748x over previous
//
#include <hip/hip_runtime.h>
#include <hip/hip_bf16.h>
#include <cstdint>

// ---------------------------------------------------------------------------
// Meta-GCN LSTM encoder.  L=2, B=4, T=8, N=2048, C=2, H=64, K=3, M=32.
// R2: gemm_k (per-lane-row scatter, latency-bound, MfmaUtil 7.5%) replaced by
// m97-style LDS-staged 128x128xBK64 GEMM with global_load_lds(16B), T2
// XOR-swizzle via pre-swizzled global source, XCD-bijective block swizzle.
// rec GEMM gets split-K=2 with fp32 partials summed inside gemm2_lstm.
// ---------------------------------------------------------------------------

typedef __hip_bfloat16 bf16;
typedef __attribute__((ext_vector_type(8))) short bf16x8;
typedef __attribute__((ext_vector_type(4))) short s16x4;
typedef __attribute__((ext_vector_type(4)))  float f32x4;

__device__ __forceinline__ short f2bf(float f) {   // RNE f32->bf16 (finite vals)
    unsigned u = __builtin_bit_cast(unsigned, f);
    return (short)((u + 0x7fffu + ((u >> 16) & 1u)) >> 16);
}

#define GLD_LDS(gaddr, laddr)                                                  \
    __builtin_amdgcn_global_load_lds(                                          \
        (const __attribute__((address_space(1))) void*)(gaddr),                \
        (__attribute__((address_space(3))) void*)(laddr), 16, 0, 0)

// ---------------- workspace layout (bytes) ----------------
#define OFF_GBF    0u           // 3*2048*2048*2      = 25165824
#define OFF_XRT0   25165824u    // 256*2048*2         = 1048576
#define OFF_XRT1   26214400u    // 1048576
#define OFF_XS0T   27262976u    // 128*2048*2         = 524288
#define OFF_HS0T   27787264u    // 2048*2048*2        = 8388608
#define OFF_S0X    36175872u    // 3*2048*64*2        = 786432
#define OFF_S1S    36962304u    // 8*3*2048*256*2     = 25165824
#define OFF_REC    62128128u    // 2sk*3*2048*256*4   = 12582912 (fp32 partials)
#define OFF_W0SW   74711040u    // 32*9*16*512*2      = 4718592
#define OFF_W1SW   79429632u    // 32*12*16*512*2     = 6291456
#define OFF_BIAS0  85721088u    // 32768
#define OFF_BIAS1  85753856u    // 32768
#define OFF_C0     85786624u    // 2097152
#define OFF_C1     87883776u    // 2097152
#define WS_NEEDED  89980928u

// ---------------------------------------------------------------------------
// prep: vectorized G f32->bf16 + transposed h/x staging + c copies.
// ---------------------------------------------------------------------------
__global__ __launch_bounds__(256) void prep_kernel(
    const float* __restrict__ G, const float* __restrict__ x_seq,
    const float* __restrict__ init_h, const float* __restrict__ init_c,
    bf16* __restrict__ Gbf, bf16* __restrict__ XrT0, bf16* __restrict__ XrT1,
    bf16* __restrict__ Xs0T, float* __restrict__ c0, float* __restrict__ c1)
{
    const int SZ_G4 = 3145728;                 // 12582912 floats / 4
    const int SZ_XR = 524288, SZ_XS = 262144, SZ_C = 524288;
    const int TOTAL = SZ_G4 + 2*SZ_XR + SZ_XS + 2*SZ_C;
    int stride = gridDim.x * 256;
    for (int idx = blockIdx.x*256 + threadIdx.x; idx < TOTAL; idx += stride) {
        int i0 = idx;
        if (i0 < SZ_G4) {
            f32x4 v = *((const f32x4*)G + i0);
            s16x4 o;
            #pragma unroll
            for (int e = 0; e < 4; e++) o[e] = f2bf(v[e]);
            *((s16x4*)Gbf + i0) = o;
            continue;
        }
        i0 -= SZ_G4;
        if (i0 < SZ_XR) {
            int n = i0 >> 11, j = i0 & 2047; int b = n >> 6, h = n & 63;
            XrT0[i0] = __float2bfloat16(init_h[((size_t)b*2048 + j)*64 + h]);
            continue;
        }
        i0 -= SZ_XR;
        if (i0 < SZ_XR) {
            int n = i0 >> 11, j = i0 & 2047; int b = n >> 6, h = n & 63;
            XrT1[i0] = __float2bfloat16(init_h[((size_t)(4+b)*2048 + j)*64 + h]);
            continue;
        }
        i0 -= SZ_XR;
        if (i0 < SZ_XS) {
            int n = i0 >> 11, j = i0 & 2047;
            float v = 0.f;
            if (n < 64) {
                int t = n >> 3, rm = n & 7, b = rm >> 1, cc = rm & 1;
                v = x_seq[(((size_t)b*8 + t)*2048 + j)*2 + cc];
            }
            Xs0T[i0] = __float2bfloat16(v);
            continue;
        }
        i0 -= SZ_XS;
        if (i0 < SZ_C) { c0[i0] = init_c[i0]; continue; }
        i0 -= SZ_C;
        c1[i0] = init_c[SZ_C + i0];
    }
}

// ---------------------------------------------------------------------------
// metaw: unchanged from R1 (passed).  W in MFMA-B-fragment-swizzled order.
// ---------------------------------------------------------------------------
__global__ __launch_bounds__(256) void metaw_kernel(
    const float* __restrict__ x_meta,
    const float* __restrict__ lw1_0, const float* __restrict__ lb1_0,
    const float* __restrict__ lw2_0, const float* __restrict__ lb2_0,
    const float* __restrict__ bw1_0, const float* __restrict__ bb1_0,
    const float* __restrict__ bw2_0, const float* __restrict__ bb2_0,
    const float* __restrict__ lw1_1, const float* __restrict__ lb1_1,
    const float* __restrict__ lw2_1, const float* __restrict__ lb2_1,
    const float* __restrict__ bw1_1, const float* __restrict__ bb1_1,
    const float* __restrict__ bw2_1, const float* __restrict__ bb2_1,
    bf16* __restrict__ W0sw, bf16* __restrict__ W1sw,
    float* __restrict__ bias0, float* __restrict__ bias1)
{
    int tid = threadIdx.x, bid = blockIdx.x;
    const float *w1, *b1v, *w2, *b2v;
    int task, r = 0;
    if (bid < 384)      { task = 0; r = bid;       w1=lw1_1; b1v=lb1_1; w2=lw2_1; b2v=lb2_1; }
    else if (bid < 582) { task = 1; r = bid - 384; w1=lw1_0; b1v=lb1_0; w2=lw2_0; b2v=lb2_0; }
    else if (bid == 582){ task = 2;                w1=bw1_0; b1v=bb1_0; w2=bw2_0; b2v=bb2_0; }
    else                { task = 3;                w1=bw1_1; b1v=bb1_1; w2=bw2_1; b2v=bb2_1; }

    __shared__ float hid[32][64];
    for (int idx = tid; idx < 2048; idx += 256) {
        int tb = idx >> 6, h = idx & 63;
        int tt = tb >> 2, b = tb & 3;
        float a = b1v[h];
        #pragma unroll
        for (int m = 0; m < 32; m++)
            a += x_meta[((size_t)b*8 + tt)*32 + m] * w1[m*64 + h];
        hid[tb][h] = fmaxf(a, 0.f);
    }
    __syncthreads();

    int o = tid;
    int RO = (task == 0) ? 98304 : (task == 1) ? 50688 : 256;
    int ro = (task >= 2) ? o : (r*256 + o);
    float col[64];
    #pragma unroll
    for (int h = 0; h < 64; h++) col[h] = w2[(size_t)h*RO + ro];
    float base = b2v[ro];

    for (int tb = 0; tb < 32; tb++) {
        float v = base;
        #pragma unroll
        for (int h = 0; h < 64; h++) v += hid[tb][h]*col[h];
        if (task == 0) {
            int rp = r, rc = rp >> 5, rr = rp & 31;
            int oc = o >> 4, l = ((rr >> 3) << 4) + (o & 15), e = rr & 7;
            W1sw[(((size_t)tb*12 + rc)*16 + oc)*512 + l*8 + e] = __float2bfloat16(v);
        } else if (task == 1) {
            int k = r/66, d = r - k*66;
            int rp = k*96 + (d < 2 ? 64 + d : d - 2);
            int rc = rp >> 5, rr = rp & 31;
            int oc = o >> 4, l = ((rr >> 3) << 4) + (o & 15), e = rr & 7;
            W0sw[(((size_t)tb*9 + rc)*16 + oc)*512 + l*8 + e] = __float2bfloat16(v);
        } else if (task == 2) bias0[tb*256 + o] = v;
        else                  bias1[tb*256 + o] = v;
    }
}

// ---------------------------------------------------------------------------
// gemm_tile<MODE>: C = Gbf[6144][2048] @ BmT[ncols][2048]^T.
// 128x128 tile, BK=64, 4 waves (2x2), wave tile 64x64, mfma 16x16x32.
// LDS [128][64] bf16 per operand with byte-swizzle  phys = r*128 + (cb ^ ((r&7)<<4)),
// staged linearly by global_load_lds(16B) from pre-inverse-swizzled global src.
// MODE 0: rec, split-K=2, fp32 partials -> dstF[sk][3][2048][256]   (192 wg)
// MODE 1: S1s, bf16 -> dst[t][3][2048][256]                         (768 wg)
// MODE 2: S0x, bf16 -> dst[3][2048][64] (B rows 64..127 are zero)   ( 48 wg)
// ---------------------------------------------------------------------------
template<int MODE>
__global__ __launch_bounds__(256) void gemm_tile(
    const short* __restrict__ A, const short* __restrict__ Bm,
    bf16* __restrict__ dstB, float* __restrict__ dstF)
{
    constexpr int NT  = (MODE == 0) ? 2 : (MODE == 1) ? 16 : 1;
    constexpr int SK  = (MODE == 0) ? 2 : 1;
    constexpr int NWG = 48 * NT * SK;
    constexpr int KLEN = 2048 / SK;

    int bid  = blockIdx.x;
    int wgid = (bid & 7) * (NWG / 8) + (bid >> 3);   // XCD-bijective (NWG%8==0)
    int mt, nt, sk;
    if (MODE == 0)      { mt = wgid >> 2; sk = (wgid >> 1) & 1; nt = wgid & 1; }
    else if (MODE == 1) { mt = wgid >> 4; nt = wgid & 15; sk = 0; }
    else                { mt = wgid; nt = 0; sk = 0; }

    int kk = mt >> 4;                 // support index (16 m-tiles per support)
    int k0 = sk * KLEN;

    __shared__ short lA[128 * 64];
    __shared__ short lB[128 * 64];

    int tid = threadIdx.x, lane = tid & 63, w = tid >> 6;
    int wr = w >> 1, wc = w & 1;

    // staging: call q stages rows (w*4+q)*8 .. +7 of the tile (1 KB of LDS).
    // lane l -> row (base + l>>3), physical granule l&7, logical granule
    // (l&7)^(l>>3)  (inverse swizzle on the SOURCE, LDS dest stays linear).
    int rloc = lane >> 3;
    int gsrc = ((lane & 7) ^ rloc) * 8;     // shorts
    const short* Ab = A  + (size_t)(mt * 128) * 2048 + k0 + gsrc;
    const short* Bb = Bm + (size_t)(nt * 128) * 2048 + k0 + gsrc;

    f32x4 acc[4][4];
    #pragma unroll
    for (int mf = 0; mf < 4; mf++)
        #pragma unroll
        for (int nf = 0; nf < 4; nf++)
            #pragma unroll
            for (int q = 0; q < 4; q++) acc[mf][nf][q] = 0.f;

    for (int kb = 0; kb < KLEN; kb += 64) {
        #pragma unroll
        for (int q = 0; q < 4; q++) {
            int row = (w * 4 + q) * 8 + rloc;
            GLD_LDS(Ab + (size_t)row * 2048 + kb, &lA[(w * 4 + q) * 512]);
            GLD_LDS(Bb + (size_t)row * 2048 + kb, &lB[(w * 4 + q) * 512]);
        }
        __syncthreads();
        #pragma unroll
        for (int ks = 0; ks < 2; ks++) {
            bf16x8 af[4], bfr[4];
            #pragma unroll
            for (int mf = 0; mf < 4; mf++) {
                int r = wr * 64 + mf * 16 + (lane & 15);
                int cb = ((lane >> 4) * 16 + ks * 64) ^ ((r & 7) << 4);
                af[mf] = *(const bf16x8*)((const char*)lA + r * 128 + cb);
            }
            #pragma unroll
            for (int nf = 0; nf < 4; nf++) {
                int r = wc * 64 + nf * 16 + (lane & 15);
                int cb = ((lane >> 4) * 16 + ks * 64) ^ ((r & 7) << 4);
                bfr[nf] = *(const bf16x8*)((const char*)lB + r * 128 + cb);
            }
            #pragma unroll
            for (int mf = 0; mf < 4; mf++)
                #pragma unroll
                for (int nf = 0; nf < 4; nf++)
                    acc[mf][nf] = __builtin_amdgcn_mfma_f32_16x16x32_bf16(
                        af[mf], bfr[nf], acc[mf][nf], 0, 0, 0);
        }
        __syncthreads();
    }

    // epilogue: D 16x16 layout: col = lane&15, row = (lane>>4)*4 + reg
    int l15 = lane & 15, lg4 = (lane >> 4) * 4;
    int ibase = (mt & 15) * 128 + wr * 64;
    #pragma unroll
    for (int mf = 0; mf < 4; mf++) {
        #pragma unroll
        for (int nf = 0; nf < 4; nf++) {
            int gn = nt * 128 + wc * 64 + nf * 16 + l15;
            #pragma unroll
            for (int reg = 0; reg < 4; reg++) {
                int gm = ibase + mf * 16 + lg4 + reg;     // 0..2047
                float v = acc[mf][nf][reg];
                if (MODE == 0) {
                    dstF[(((size_t)sk * 3 + kk) * 2048 + gm) * 256 + gn] = v;
                } else if (MODE == 1) {
                    int tt = gn >> 8, c = gn & 255;
                    dstB[(((size_t)tt * 3 + kk) * 2048 + gm) * 256 + c] = __float2bfloat16(v);
                } else {
                    if (gn < 64)
                        dstB[((size_t)kk * 2048 + gm) * 64 + gn] = __float2bfloat16(v);
                }
            }
        }
    }
}

// ---------------------------------------------------------------------------
// gemm2_lstm: gates = sup @ W[t,b] + bias -> LSTM update.  No LDS, no barriers.
// rec is now fp32 split-K partials [2][3][2048][256]: summed while building
// the bf16 A-fragment.
// ---------------------------------------------------------------------------
__device__ __forceinline__ bf16x8 sum2bf(const float* __restrict__ p0,
                                         const float* __restrict__ p1)
{
    f32x4 a = *(const f32x4*)p0, b = *(const f32x4*)(p0 + 4);
    f32x4 c = *(const f32x4*)p1, d = *(const f32x4*)(p1 + 4);
    bf16x8 r;
    #pragma unroll
    for (int e = 0; e < 4; e++) {
        r[e]     = f2bf(a[e] + c[e]);
        r[e + 4] = f2bf(b[e] + d[e]);
    }
    return r;
}

template<int LAYER>
__global__ __launch_bounds__(256) void gemm2_lstm(
    const float* __restrict__ recF, const short* __restrict__ Sstat,
    const short* __restrict__ Wsw, const float* __restrict__ bias,
    float* __restrict__ cbuf, bf16* __restrict__ xrT, bf16* __restrict__ hs0T,
    float* __restrict__ out, int t)
{
    constexpr int NC = (LAYER == 0) ? 9 : 12;
    int tid = threadIdx.x, lane = tid & 63, w = tid >> 6;
    int b = blockIdx.x & 3, it = blockIdx.x >> 2;
    int tb = t*4 + b;
    int l15 = lane & 15, lg = lane >> 4;
    int iA0 = it*32 + l15;
    int iA1 = iA0 + 16;

    f32x4 acc[2][4];
    #pragma unroll
    for (int mi = 0; mi < 2; mi++)
        #pragma unroll
        for (int g = 0; g < 4; g++)
            #pragma unroll
            for (int q = 0; q < 4; q++) acc[mi][g][q] = 0.f;

    const short* WswT = Wsw + (size_t)tb*NC*16*512;

    #pragma unroll
    for (int rc = 0; rc < NC; rc++) {
        bf16x8 a0, a1;
        if (LAYER == 1) {
            int kkx = rc >> 2, d0 = (rc & 3)*32;
            if (d0 < 64) {      // static part from S1s (bf16)
                const short* src = Sstat + (size_t)t*3*2048*256;
                int col = b*64 + d0 + lg*8;
                a0 = *(const bf16x8*)(src + ((size_t)kkx*2048 + iA0)*256 + col);
                a1 = *(const bf16x8*)(src + ((size_t)kkx*2048 + iA1)*256 + col);
            } else {            // recurrent part: sum 2 fp32 partials
                int col = b*64 + (d0 - 64) + lg*8;
                const float* q00 = recF + ((size_t)kkx*2048 + iA0)*256 + col;
                const float* q01 = recF + ((size_t)(3 + kkx)*2048 + iA0)*256 + col;
                const float* q10 = recF + ((size_t)kkx*2048 + iA1)*256 + col;
                const float* q11 = recF + ((size_t)(3 + kkx)*2048 + iA1)*256 + col;
                a0 = sum2bf(q00, q01);
                a1 = sum2bf(q10, q11);
            }
        } else {
            int kkx = rc/3, dd = rc - kkx*3;
            if (dd < 2) {       // recurrent part
                int col = b*64 + dd*32 + lg*8;
                const float* q00 = recF + ((size_t)kkx*2048 + iA0)*256 + col;
                const float* q01 = recF + ((size_t)(3 + kkx)*2048 + iA0)*256 + col;
                const float* q10 = recF + ((size_t)kkx*2048 + iA1)*256 + col;
                const float* q11 = recF + ((size_t)(3 + kkx)*2048 + iA1)*256 + col;
                a0 = sum2bf(q00, q01);
                a1 = sum2bf(q10, q11);
            } else {            // x static cols (2 valid + 30 pad)
                #pragma unroll
                for (int e = 0; e < 8; e++) { a0[e] = 0; a1[e] = 0; }
                if (lg == 0) {
                    unsigned v0 = *(const unsigned*)(Sstat + ((size_t)kkx*2048 + iA0)*64 + t*8 + b*2);
                    unsigned v1 = *(const unsigned*)(Sstat + ((size_t)kkx*2048 + iA1)*64 + t*8 + b*2);
                    a0[0] = (short)(v0 & 0xffff); a0[1] = (short)(v0 >> 16);
                    a1[0] = (short)(v1 & 0xffff); a1[1] = (short)(v1 >> 16);
                }
            }
        }
        #pragma unroll
        for (int g = 0; g < 4; g++) {
            bf16x8 wf = *(const bf16x8*)(WswT + (((size_t)rc*16 + (g*4 + w))*64 + lane)*8);
            acc[0][g] = __builtin_amdgcn_mfma_f32_16x16x32_bf16(a0, wf, acc[0][g], 0, 0, 0);
            acc[1][g] = __builtin_amdgcn_mfma_f32_16x16x32_bf16(a1, wf, acc[1][g], 0, 0, 0);
        }
    }

    int hcol = w*16 + l15;
    float bia[4];
    #pragma unroll
    for (int g = 0; g < 4; g++) bia[g] = bias[tb*256 + g*64 + hcol];

    #pragma unroll
    for (int mi = 0; mi < 2; mi++) {
        #pragma unroll
        for (int r = 0; r < 4; r++) {
            int i = it*32 + mi*16 + lg*4 + r;
            float gi = acc[mi][0][r] + bia[0];
            float gf = acc[mi][1][r] + bia[1];
            float go = acc[mi][2][r] + bia[2];
            float gg = acc[mi][3][r] + bia[3];
            size_t cidx = ((size_t)b*2048 + i)*64 + hcol;
            float c_old = cbuf[cidx];
            float si = 1.f/(1.f + __expf(-gi));
            float sf = 1.f/(1.f + __expf(-gf));
            float so = 1.f/(1.f + __expf(-go));
            float cn = sf*c_old + si*tanhf(gg);
            float hn = so*tanhf(cn);
            cbuf[cidx] = cn;
            bf16 hb = __float2bfloat16(hn);
            xrT[((size_t)b*64 + hcol)*2048 + i] = hb;
            if (LAYER == 0)
                hs0T[((size_t)t*256 + b*64 + hcol)*2048 + i] = hb;
            if (t == 7) {
                out[(((size_t)LAYER*4 + b)*2048 + i)*64 + hcol]       = hn;
                out[(((size_t)(2 + LAYER)*4 + b)*2048 + i)*64 + hcol] = cn;
            }
        }
    }
}

// ---------------------------------------------------------------------------
extern "C" void kernel_launch(void* const* d_in, const int* in_sizes, int n_in,
                              void* d_out, int out_size, void* d_ws, size_t ws_size,
                              hipStream_t stream)
{
    const float* G      = (const float*)d_in[0];
    const float* x_seq  = (const float*)d_in[1];
    const float* init_h = (const float*)d_in[2];
    const float* init_c = (const float*)d_in[3];
    const float* x_meta = (const float*)d_in[4];
    const float* lw1_0 = (const float*)d_in[5],  *lb1_0 = (const float*)d_in[6];
    const float* lw2_0 = (const float*)d_in[7],  *lb2_0 = (const float*)d_in[8];
    const float* bw1_0 = (const float*)d_in[9],  *bb1_0 = (const float*)d_in[10];
    const float* bw2_0 = (const float*)d_in[11], *bb2_0 = (const float*)d_in[12];
    const float* lw1_1 = (const float*)d_in[13], *lb1_1 = (const float*)d_in[14];
    const float* lw2_1 = (const float*)d_in[15], *lb2_1 = (const float*)d_in[16];
    const float* bw1_1 = (const float*)d_in[17], *bb1_1 = (const float*)d_in[18];
    const float* bw2_1 = (const float*)d_in[19], *bb2_1 = (const float*)d_in[20];

    if (ws_size < WS_NEEDED) return;

    char* ws = (char*)d_ws;
    bf16*  Gbf   = (bf16*) (ws + OFF_GBF);
    bf16*  XrT0  = (bf16*) (ws + OFF_XRT0);
    bf16*  XrT1  = (bf16*) (ws + OFF_XRT1);
    bf16*  Xs0T  = (bf16*) (ws + OFF_XS0T);
    bf16*  hs0T  = (bf16*) (ws + OFF_HS0T);
    bf16*  S0x   = (bf16*) (ws + OFF_S0X);
    bf16*  S1s   = (bf16*) (ws + OFF_S1S);
    float* recF  = (float*)(ws + OFF_REC);
    bf16*  W0sw  = (bf16*) (ws + OFF_W0SW);
    bf16*  W1sw  = (bf16*) (ws + OFF_W1SW);
    float* bias0 = (float*)(ws + OFF_BIAS0);
    float* bias1 = (float*)(ws + OFF_BIAS1);
    float* c0    = (float*)(ws + OFF_C0);
    float* c1    = (float*)(ws + OFF_C1);
    float* out   = (float*)d_out;

    prep_kernel<<<4096, 256, 0, stream>>>(G, x_seq, init_h, init_c,
                                          Gbf, XrT0, XrT1, Xs0T, c0, c1);
    metaw_kernel<<<584, 256, 0, stream>>>(x_meta,
        lw1_0, lb1_0, lw2_0, lb2_0, bw1_0, bb1_0, bw2_0, bb2_0,
        lw1_1, lb1_1, lw2_1, lb2_1, bw1_1, bb1_1, bw2_1, bb2_1,
        W0sw, W1sw, bias0, bias1);

    gemm_tile<2><<<48, 256, 0, stream>>>((const short*)Gbf, (const short*)Xs0T,
                                         S0x, nullptr);

    for (int t = 0; t < 8; t++) {
        gemm_tile<0><<<192, 256, 0, stream>>>((const short*)Gbf, (const short*)XrT0,
                                              nullptr, recF);
        gemm2_lstm<0><<<256, 256, 0, stream>>>(recF, (const short*)S0x,
            (const short*)W0sw, bias0, c0, XrT0, hs0T, out, t);
    }

    gemm_tile<1><<<768, 256, 0, stream>>>((const short*)Gbf, (const short*)hs0T,
                                          S1s, nullptr);

    for (int t = 0; t < 8; t++) {
        gemm_tile<0><<<192, 256, 0, stream>>>((const short*)Gbf, (const short*)XrT1,
                                              nullptr, recF);
        gemm2_lstm<1><<<256, 256, 0, stream>>>(recF, (const short*)S1s,
            (const short*)W1sw, bias1, c1, XrT1, nullptr, out, t);
    }
}

// Round 3
// 570.214 us; speedup vs baseline: 2.2206x; 1.3259x over previous
//
#include <hip/hip_runtime.h>
#include <hip/hip_bf16.h>
#include <cstdint>

// ---------------------------------------------------------------------------
// Meta-GCN LSTM encoder.  L=2, B=4, T=8, N=2048, C=2, H=64, K=3, M=32.
// R3: rec-GEMM + gemm2 + LSTM fused into ONE kernel per step (step_fused).
//  - block (it,b): computes sup_rec = G[k][32 rows] @ h_b in-block (MFMA
//    32x32x16, K-split over 4 waves, LDS f32 reduce), then gemm2+LSTM.
//  - XCD-pinned block mapping keeps each XCD's 3MB G slice L2-hot all steps.
// S0x/S1s/metaw/prep unchanged from R2 (proven).
// ---------------------------------------------------------------------------

typedef __hip_bfloat16 bf16;
typedef __attribute__((ext_vector_type(8))) short bf16x8;
typedef __attribute__((ext_vector_type(4))) short s16x4;
typedef __attribute__((ext_vector_type(4)))  float f32x4;
typedef __attribute__((ext_vector_type(16))) float f32x16;

__device__ __forceinline__ short f2bf(float f) {   // RNE f32->bf16
    unsigned u = __builtin_bit_cast(unsigned, f);
    return (short)((u + 0x7fffu + ((u >> 16) & 1u)) >> 16);
}

#define GLD_LDS(gaddr, laddr)                                                  \
    __builtin_amdgcn_global_load_lds(                                          \
        (const __attribute__((address_space(1))) void*)(gaddr),                \
        (__attribute__((address_space(3))) void*)(laddr), 16, 0, 0)

// ---------------- workspace layout (bytes) ----------------
#define OFF_GBF    0u
#define OFF_XRT0   25165824u
#define OFF_XRT1   26214400u
#define OFF_XS0T   27262976u
#define OFF_HS0T   27787264u
#define OFF_S0X    36175872u
#define OFF_S1S    36962304u
#define OFF_REC    62128128u    // unused in R3
#define OFF_W0SW   74711040u
#define OFF_W1SW   79429632u
#define OFF_BIAS0  85721088u
#define OFF_BIAS1  85753856u
#define OFF_C0     85786624u
#define OFF_C1     87883776u
#define WS_NEEDED  89980928u

// ---------------------------------------------------------------------------
__global__ __launch_bounds__(256) void prep_kernel(
    const float* __restrict__ G, const float* __restrict__ x_seq,
    const float* __restrict__ init_h, const float* __restrict__ init_c,
    bf16* __restrict__ Gbf, bf16* __restrict__ XrT0, bf16* __restrict__ XrT1,
    bf16* __restrict__ Xs0T, float* __restrict__ c0, float* __restrict__ c1)
{
    const int SZ_G4 = 3145728;
    const int SZ_XR = 524288, SZ_XS = 262144, SZ_C = 524288;
    const int TOTAL = SZ_G4 + 2*SZ_XR + SZ_XS + 2*SZ_C;
    int stride = gridDim.x * 256;
    for (int idx = blockIdx.x*256 + threadIdx.x; idx < TOTAL; idx += stride) {
        int i0 = idx;
        if (i0 < SZ_G4) {
            f32x4 v = *((const f32x4*)G + i0);
            s16x4 o;
            #pragma unroll
            for (int e = 0; e < 4; e++) o[e] = f2bf(v[e]);
            *((s16x4*)Gbf + i0) = o;
            continue;
        }
        i0 -= SZ_G4;
        if (i0 < SZ_XR) {
            int n = i0 >> 11, j = i0 & 2047; int b = n >> 6, h = n & 63;
            XrT0[i0] = __float2bfloat16(init_h[((size_t)b*2048 + j)*64 + h]);
            continue;
        }
        i0 -= SZ_XR;
        if (i0 < SZ_XR) {
            int n = i0 >> 11, j = i0 & 2047; int b = n >> 6, h = n & 63;
            XrT1[i0] = __float2bfloat16(init_h[((size_t)(4+b)*2048 + j)*64 + h]);
            continue;
        }
        i0 -= SZ_XR;
        if (i0 < SZ_XS) {
            int n = i0 >> 11, j = i0 & 2047;
            float v = 0.f;
            if (n < 64) {
                int t = n >> 3, rm = n & 7, b = rm >> 1, cc = rm & 1;
                v = x_seq[(((size_t)b*8 + t)*2048 + j)*2 + cc];
            }
            Xs0T[i0] = __float2bfloat16(v);
            continue;
        }
        i0 -= SZ_XS;
        if (i0 < SZ_C) { c0[i0] = init_c[i0]; continue; }
        i0 -= SZ_C;
        c1[i0] = init_c[SZ_C + i0];
    }
}

// ---------------------------------------------------------------------------
__global__ __launch_bounds__(256) void metaw_kernel(
    const float* __restrict__ x_meta,
    const float* __restrict__ lw1_0, const float* __restrict__ lb1_0,
    const float* __restrict__ lw2_0, const float* __restrict__ lb2_0,
    const float* __restrict__ bw1_0, const float* __restrict__ bb1_0,
    const float* __restrict__ bw2_0, const float* __restrict__ bb2_0,
    const float* __restrict__ lw1_1, const float* __restrict__ lb1_1,
    const float* __restrict__ lw2_1, const float* __restrict__ lb2_1,
    const float* __restrict__ bw1_1, const float* __restrict__ bb1_1,
    const float* __restrict__ bw2_1, const float* __restrict__ bb2_1,
    bf16* __restrict__ W0sw, bf16* __restrict__ W1sw,
    float* __restrict__ bias0, float* __restrict__ bias1)
{
    int tid = threadIdx.x, bid = blockIdx.x;
    const float *w1, *b1v, *w2, *b2v;
    int task, r = 0;
    if (bid < 384)      { task = 0; r = bid;       w1=lw1_1; b1v=lb1_1; w2=lw2_1; b2v=lb2_1; }
    else if (bid < 582) { task = 1; r = bid - 384; w1=lw1_0; b1v=lb1_0; w2=lw2_0; b2v=lb2_0; }
    else if (bid == 582){ task = 2;                w1=bw1_0; b1v=bb1_0; w2=bw2_0; b2v=bb2_0; }
    else                { task = 3;                w1=bw1_1; b1v=bb1_1; w2=bw2_1; b2v=bb2_1; }

    __shared__ float hid[32][64];
    for (int idx = tid; idx < 2048; idx += 256) {
        int tb = idx >> 6, h = idx & 63;
        int tt = tb >> 2, b = tb & 3;
        float a = b1v[h];
        #pragma unroll
        for (int m = 0; m < 32; m++)
            a += x_meta[((size_t)b*8 + tt)*32 + m] * w1[m*64 + h];
        hid[tb][h] = fmaxf(a, 0.f);
    }
    __syncthreads();

    int o = tid;
    int RO = (task == 0) ? 98304 : (task == 1) ? 50688 : 256;
    int ro = (task >= 2) ? o : (r*256 + o);
    float col[64];
    #pragma unroll
    for (int h = 0; h < 64; h++) col[h] = w2[(size_t)h*RO + ro];
    float base = b2v[ro];

    for (int tb = 0; tb < 32; tb++) {
        float v = base;
        #pragma unroll
        for (int h = 0; h < 64; h++) v += hid[tb][h]*col[h];
        if (task == 0) {
            int rp = r, rc = rp >> 5, rr = rp & 31;
            int oc = o >> 4, l = ((rr >> 3) << 4) + (o & 15), e = rr & 7;
            W1sw[(((size_t)tb*12 + rc)*16 + oc)*512 + l*8 + e] = __float2bfloat16(v);
        } else if (task == 1) {
            int k = r/66, d = r - k*66;
            int rp = k*96 + (d < 2 ? 64 + d : d - 2);
            int rc = rp >> 5, rr = rp & 31;
            int oc = o >> 4, l = ((rr >> 3) << 4) + (o & 15), e = rr & 7;
            W0sw[(((size_t)tb*9 + rc)*16 + oc)*512 + l*8 + e] = __float2bfloat16(v);
        } else if (task == 2) bias0[tb*256 + o] = v;
        else                  bias1[tb*256 + o] = v;
    }
}

// ---------------------------------------------------------------------------
// gemm_tile<MODE>: unchanged from R2 (proven).  MODE 1: S1s;  MODE 2: S0x.
// ---------------------------------------------------------------------------
template<int MODE>
__global__ __launch_bounds__(256) void gemm_tile(
    const short* __restrict__ A, const short* __restrict__ Bm,
    bf16* __restrict__ dstB)
{
    constexpr int NT  = (MODE == 1) ? 16 : 1;
    constexpr int NWG = 48 * NT;

    int bid  = blockIdx.x;
    int wgid = (bid & 7) * (NWG / 8) + (bid >> 3);
    int mt, nt;
    if (MODE == 1) { mt = wgid >> 4; nt = wgid & 15; }
    else           { mt = wgid; nt = 0; }

    int kk = mt >> 4;

    __shared__ short lA[128 * 64];
    __shared__ short lB[128 * 64];

    int tid = threadIdx.x, lane = tid & 63, w = tid >> 6;
    int wr = w >> 1, wc = w & 1;

    int rloc = lane >> 3;
    int gsrc = ((lane & 7) ^ rloc) * 8;
    const short* Ab = A  + (size_t)(mt * 128) * 2048 + gsrc;
    const short* Bb = Bm + (size_t)(nt * 128) * 2048 + gsrc;

    f32x4 acc[4][4];
    #pragma unroll
    for (int mf = 0; mf < 4; mf++)
        #pragma unroll
        for (int nf = 0; nf < 4; nf++)
            #pragma unroll
            for (int q = 0; q < 4; q++) acc[mf][nf][q] = 0.f;

    for (int kb = 0; kb < 2048; kb += 64) {
        #pragma unroll
        for (int q = 0; q < 4; q++) {
            int row = (w * 4 + q) * 8 + rloc;
            GLD_LDS(Ab + (size_t)row * 2048 + kb, &lA[(w * 4 + q) * 512]);
            GLD_LDS(Bb + (size_t)row * 2048 + kb, &lB[(w * 4 + q) * 512]);
        }
        __syncthreads();
        #pragma unroll
        for (int ks = 0; ks < 2; ks++) {
            bf16x8 af[4], bfr[4];
            #pragma unroll
            for (int mf = 0; mf < 4; mf++) {
                int r = wr * 64 + mf * 16 + (lane & 15);
                int cb = ((lane >> 4) * 16 + ks * 64) ^ ((r & 7) << 4);
                af[mf] = *(const bf16x8*)((const char*)lA + r * 128 + cb);
            }
            #pragma unroll
            for (int nf = 0; nf < 4; nf++) {
                int r = wc * 64 + nf * 16 + (lane & 15);
                int cb = ((lane >> 4) * 16 + ks * 64) ^ ((r & 7) << 4);
                bfr[nf] = *(const bf16x8*)((const char*)lB + r * 128 + cb);
            }
            #pragma unroll
            for (int mf = 0; mf < 4; mf++)
                #pragma unroll
                for (int nf = 0; nf < 4; nf++)
                    acc[mf][nf] = __builtin_amdgcn_mfma_f32_16x16x32_bf16(
                        af[mf], bfr[nf], acc[mf][nf], 0, 0, 0);
        }
        __syncthreads();
    }

    int l15 = lane & 15, lg4 = (lane >> 4) * 4;
    int ibase = (mt & 15) * 128 + wr * 64;
    #pragma unroll
    for (int mf = 0; mf < 4; mf++) {
        #pragma unroll
        for (int nf = 0; nf < 4; nf++) {
            int gn = nt * 128 + wc * 64 + nf * 16 + l15;
            #pragma unroll
            for (int reg = 0; reg < 4; reg++) {
                int gm = ibase + mf * 16 + lg4 + reg;
                float v = acc[mf][nf][reg];
                if (MODE == 1) {
                    int tt = gn >> 8, c = gn & 255;
                    dstB[(((size_t)tt * 3 + kk) * 2048 + gm) * 256 + c] = __float2bfloat16(v);
                } else {
                    if (gn < 64)
                        dstB[((size_t)kk * 2048 + gm) * 64 + gn] = __float2bfloat16(v);
                }
            }
        }
    }
}

// ---------------------------------------------------------------------------
// step_fused<LAYER>: one launch per time step.
// Grid 256 = it(64) x b(4), XCD-pinned: it = (bid&7)*8 + (bid>>3)/4.
// Phase 1: sup_rec[k][32i][64d] = G[k] @ h_b  (MFMA 32x32x16, 4-wave K-split,
//          BK=128 double-buffered global_load_lds staging, XOR-swizzled LDS).
// Phase 2: LDS f32 reduce across waves -> bf16 sup_lds [32][pad 512B] swizzled.
// Phase 3: gemm2 (R2 math; rec chunks from sup_lds) + LSTM epilogue.
// ---------------------------------------------------------------------------
template<int LAYER>
__global__ __launch_bounds__(256, 1) void step_fused(
    const short* __restrict__ Gbf, const short* __restrict__ Sstat,
    const short* __restrict__ Wsw, const float* __restrict__ bias,
    float* __restrict__ cbuf, bf16* __restrict__ xrT, bf16* __restrict__ hs0T,
    float* __restrict__ out, int t)
{
    constexpr int NC = (LAYER == 0) ? 9 : 12;
    // [0,81920): staging dbuf (lG 24KB + lH 16KB per buf, 40960 stride)
    // [0,98304): phase-2 f32 partials (aliased; used after staging done)
    // [98304,114688): sup_lds: 32 rows x 512 B, XOR-swizzled ((i&15)<<4)
    __shared__ char lds[114688];
    char* SUP = lds + 98304;

    int tid = threadIdx.x, lane = tid & 63, w = tid >> 6;
    int bid = blockIdx.x;
    int q = bid >> 3;
    int it = (bid & 7) * 8 + (q >> 2), b = q & 3;
    int i0 = it * 32;
    int l31 = lane & 31, eo = lane >> 5, l15 = lane & 15, lg = lane >> 4;

    const short* xr = (const short*)xrT;

    f32x16 acc6[6];
    #pragma unroll
    for (int f = 0; f < 6; f++)
        #pragma unroll
        for (int r = 0; r < 16; r++) acc6[f][r] = 0.f;

    auto STAGE = [&](int bufi, int jb) {
        char* base = lds + bufi * 40960;
        #pragma unroll
        for (int qq = 0; qq < 6; qq++) {           // G: 3x32 rows x 128 j
            int g = tid + qq * 256;
            int kr = g >> 4, p = g & 15;
            int k = kr >> 5, row = kr & 31;
            const short* src = Gbf + ((size_t)(k * 2048 + i0 + row)) * 2048
                               + jb + ((p ^ (row & 15)) * 8);
            GLD_LDS(src, base + g * 16);
        }
        char* hbase = base + 24576;
        #pragma unroll
        for (int qq = 0; qq < 4; qq++) {           // h^T: 64 d-rows x 128 j
            int g = tid + qq * 256;
            int d = g >> 4, p = g & 15;
            const short* src = xr + ((size_t)(b * 64 + d)) * 2048
                               + jb + ((p ^ (d & 15)) * 8);
            GLD_LDS(src, hbase + g * 16);
        }
    };

    auto COMPUTE = [&](int bufi) {
        char* base = lds + bufi * 40960;
        char* hbase = base + 24576;
        #pragma unroll
        for (int ks = 0; ks < 2; ks++) {
            int jl2 = w * 64 + ks * 32 + eo * 16;  // byte offset of this wave's j-slice
            bf16x8 a[3], bb[2];
            #pragma unroll
            for (int k = 0; k < 3; k++)
                a[k] = *(const bf16x8*)(base + k * 8192 + l31 * 256
                                        + (jl2 ^ ((l31 & 15) << 4)));
            #pragma unroll
            for (int dc = 0; dc < 2; dc++) {
                int d = dc * 32 + l31;
                bb[dc] = *(const bf16x8*)(hbase + d * 256 + (jl2 ^ ((d & 15) << 4)));
            }
            #pragma unroll
            for (int k = 0; k < 3; k++)
                #pragma unroll
                for (int dc = 0; dc < 2; dc++)
                    acc6[k * 2 + dc] = __builtin_amdgcn_mfma_f32_32x32x16_bf16(
                        a[k], bb[dc], acc6[k * 2 + dc], 0, 0, 0);
        }
    };

    STAGE(0, 0);
    __syncthreads();
    for (int m = 0; m < 16; m++) {
        if (m < 15) STAGE((m + 1) & 1, (m + 1) * 128);
        COMPUTE(m & 1);
        __syncthreads();
    }

    // phase 2a: write per-wave f32 partials
    #pragma unroll
    for (int f = 0; f < 6; f++) {
        float* pb = (float*)(lds + (size_t)(w * 6 + f) * 4096) + lane * 16;
        #pragma unroll
        for (int qq = 0; qq < 4; qq++) {
            f32x4 v;
            #pragma unroll
            for (int r = 0; r < 4; r++) v[r] = acc6[f][qq * 4 + r];
            *(f32x4*)(pb + qq * 4) = v;
        }
    }
    __syncthreads();

    // phase 2b: reduce 4 partials -> bf16 sup_lds (swizzled)
    #pragma unroll
    for (int c2 = 0; c2 < 6; c2++) {
        int cid = c2 * 256 + tid;
        int f = cid >> 8, p0 = (cid & 255) * 4;
        f32x4 s = *(const f32x4*)(lds + (size_t)f * 4096 + p0 * 4);
        #pragma unroll
        for (int ww = 1; ww < 4; ww++) {
            f32x4 v = *(const f32x4*)(lds + (size_t)(ww * 6 + f) * 4096 + p0 * 4);
            s[0] += v[0]; s[1] += v[1]; s[2] += v[2]; s[3] += v[3];
        }
        int k = f >> 1, dc = f & 1;
        int col = (p0 >> 4) & 31, hi = p0 >> 9, r0 = p0 & 15;
        int ib = (r0 >> 2) * 8 + hi * 4;
        int dp = k * 64 + dc * 32 + col;
        #pragma unroll
        for (int u = 0; u < 4; u++) {
            int i = ib + u;
            *(short*)(SUP + i * 512 + ((dp * 2) ^ ((i & 15) << 4))) = f2bf(s[u]);
        }
    }
    __syncthreads();

    // phase 3: gemm2 (gates = sup @ W + bias) + LSTM
    f32x4 ag[2][4];
    #pragma unroll
    for (int mi = 0; mi < 2; mi++)
        #pragma unroll
        for (int g = 0; g < 4; g++)
            #pragma unroll
            for (int r = 0; r < 4; r++) ag[mi][g][r] = 0.f;

    const short* WswT = Wsw + (size_t)(t * 4 + b) * NC * 16 * 512;

    #pragma unroll
    for (int rc = 0; rc < NC; rc++) {
        bf16x8 a0, a1;
        if (LAYER == 1) {
            int kk = rc >> 2, dq = rc & 3;
            if (dq < 2) {
                const short* src = Sstat + (size_t)t * 3 * 2048 * 256;
                int col = b * 64 + dq * 32 + lg * 8;
                a0 = *(const bf16x8*)(src + ((size_t)kk * 2048 + i0 + l15) * 256 + col);
                a1 = *(const bf16x8*)(src + ((size_t)kk * 2048 + i0 + 16 + l15) * 256 + col);
            } else {
                int dpb = (kk * 64 + (dq - 2) * 32 + lg * 8) * 2;
                a0 = *(const bf16x8*)(SUP + l15 * 512 + (dpb ^ (l15 << 4)));
                a1 = *(const bf16x8*)(SUP + (l15 + 16) * 512 + (dpb ^ (l15 << 4)));
            }
        } else {
            int kk = rc / 3, dd = rc - kk * 3;
            if (dd < 2) {
                int dpb = (kk * 64 + dd * 32 + lg * 8) * 2;
                a0 = *(const bf16x8*)(SUP + l15 * 512 + (dpb ^ (l15 << 4)));
                a1 = *(const bf16x8*)(SUP + (l15 + 16) * 512 + (dpb ^ (l15 << 4)));
            } else {
                #pragma unroll
                for (int e = 0; e < 8; e++) { a0[e] = 0; a1[e] = 0; }
                if (lg == 0) {
                    unsigned v0 = *(const unsigned*)(Sstat + ((size_t)kk * 2048 + i0 + l15) * 64 + t * 8 + b * 2);
                    unsigned v1 = *(const unsigned*)(Sstat + ((size_t)kk * 2048 + i0 + 16 + l15) * 64 + t * 8 + b * 2);
                    a0[0] = (short)(v0 & 0xffff); a0[1] = (short)(v0 >> 16);
                    a1[0] = (short)(v1 & 0xffff); a1[1] = (short)(v1 >> 16);
                }
            }
        }
        #pragma unroll
        for (int g = 0; g < 4; g++) {
            bf16x8 wf = *(const bf16x8*)(WswT + (((size_t)rc * 16 + (g * 4 + w)) * 64 + lane) * 8);
            ag[0][g] = __builtin_amdgcn_mfma_f32_16x16x32_bf16(a0, wf, ag[0][g], 0, 0, 0);
            ag[1][g] = __builtin_amdgcn_mfma_f32_16x16x32_bf16(a1, wf, ag[1][g], 0, 0, 0);
        }
    }

    int hcol = w * 16 + l15;
    float bia[4];
    #pragma unroll
    for (int g = 0; g < 4; g++) bia[g] = bias[(t * 4 + b) * 256 + g * 64 + hcol];

    #pragma unroll
    for (int mi = 0; mi < 2; mi++) {
        #pragma unroll
        for (int r = 0; r < 4; r++) {
            int i = i0 + mi * 16 + lg * 4 + r;
            float gi = ag[mi][0][r] + bia[0];
            float gf = ag[mi][1][r] + bia[1];
            float go = ag[mi][2][r] + bia[2];
            float gg = ag[mi][3][r] + bia[3];
            size_t cidx = ((size_t)b * 2048 + i) * 64 + hcol;
            float c_old = cbuf[cidx];
            float si = 1.f / (1.f + __expf(-gi));
            float sf = 1.f / (1.f + __expf(-gf));
            float so = 1.f / (1.f + __expf(-go));
            float cn = sf * c_old + si * tanhf(gg);
            float hn = so * tanhf(cn);
            cbuf[cidx] = cn;
            bf16 hb = __float2bfloat16(hn);
            xrT[((size_t)b * 64 + hcol) * 2048 + i] = hb;
            if (LAYER == 0)
                hs0T[((size_t)t * 256 + b * 64 + hcol) * 2048 + i] = hb;
            if (t == 7) {
                out[(((size_t)LAYER * 4 + b) * 2048 + i) * 64 + hcol]       = hn;
                out[(((size_t)(2 + LAYER) * 4 + b) * 2048 + i) * 64 + hcol] = cn;
            }
        }
    }
}

// ---------------------------------------------------------------------------
extern "C" void kernel_launch(void* const* d_in, const int* in_sizes, int n_in,
                              void* d_out, int out_size, void* d_ws, size_t ws_size,
                              hipStream_t stream)
{
    const float* G      = (const float*)d_in[0];
    const float* x_seq  = (const float*)d_in[1];
    const float* init_h = (const float*)d_in[2];
    const float* init_c = (const float*)d_in[3];
    const float* x_meta = (const float*)d_in[4];
    const float* lw1_0 = (const float*)d_in[5],  *lb1_0 = (const float*)d_in[6];
    const float* lw2_0 = (const float*)d_in[7],  *lb2_0 = (const float*)d_in[8];
    const float* bw1_0 = (const float*)d_in[9],  *bb1_0 = (const float*)d_in[10];
    const float* bw2_0 = (const float*)d_in[11], *bb2_0 = (const float*)d_in[12];
    const float* lw1_1 = (const float*)d_in[13], *lb1_1 = (const float*)d_in[14];
    const float* lw2_1 = (const float*)d_in[15], *lb2_1 = (const float*)d_in[16];
    const float* bw1_1 = (const float*)d_in[17], *bb1_1 = (const float*)d_in[18];
    const float* bw2_1 = (const float*)d_in[19], *bb2_1 = (const float*)d_in[20];

    if (ws_size < WS_NEEDED) return;

    char* ws = (char*)d_ws;
    bf16*  Gbf   = (bf16*) (ws + OFF_GBF);
    bf16*  XrT0  = (bf16*) (ws + OFF_XRT0);
    bf16*  XrT1  = (bf16*) (ws + OFF_XRT1);
    bf16*  Xs0T  = (bf16*) (ws + OFF_XS0T);
    bf16*  hs0T  = (bf16*) (ws + OFF_HS0T);
    bf16*  S0x   = (bf16*) (ws + OFF_S0X);
    bf16*  S1s   = (bf16*) (ws + OFF_S1S);
    bf16*  W0sw  = (bf16*) (ws + OFF_W0SW);
    bf16*  W1sw  = (bf16*) (ws + OFF_W1SW);
    float* bias0 = (float*)(ws + OFF_BIAS0);
    float* bias1 = (float*)(ws + OFF_BIAS1);
    float* c0    = (float*)(ws + OFF_C0);
    float* c1    = (float*)(ws + OFF_C1);
    float* out   = (float*)d_out;

    prep_kernel<<<4096, 256, 0, stream>>>(G, x_seq, init_h, init_c,
                                          Gbf, XrT0, XrT1, Xs0T, c0, c1);
    metaw_kernel<<<584, 256, 0, stream>>>(x_meta,
        lw1_0, lb1_0, lw2_0, lb2_0, bw1_0, bb1_0, bw2_0, bb2_0,
        lw1_1, lb1_1, lw2_1, lb2_1, bw1_1, bb1_1, bw2_1, bb2_1,
        W0sw, W1sw, bias0, bias1);

    gemm_tile<2><<<48, 256, 0, stream>>>((const short*)Gbf, (const short*)Xs0T, S0x);

    for (int t = 0; t < 8; t++)
        step_fused<0><<<256, 256, 0, stream>>>((const short*)Gbf, (const short*)S0x,
            (const short*)W0sw, bias0, c0, XrT0, hs0T, out, t);

    gemm_tile<1><<<768, 256, 0, stream>>>((const short*)Gbf, (const short*)hs0T, S1s);

    for (int t = 0; t < 8; t++)
        step_fused<1><<<256, 256, 0, stream>>>((const short*)Gbf, (const short*)S1s,
            (const short*)W1sw, bias1, c1, XrT1, nullptr, out, t);
}

// Round 4
// 548.722 us; speedup vs baseline: 2.3076x; 1.0392x over previous
//
#include <hip/hip_runtime.h>
#include <hip/hip_bf16.h>
#include <cstdint>

// ---------------------------------------------------------------------------
// Meta-GCN LSTM encoder.  L=2, B=4, T=8, N=2048, C=2, H=64, K=3, M=32.
// R4: step_fused gets T3/T4 pipelining — triple-buffered staging, issue-ahead-2,
// ONE raw s_barrier per 128-j chunk with counted s_waitcnt vmcnt(10) (never 0
// in the main loop).  Math/layouts identical to R3 (passed, absmax 0.00195).
// ---------------------------------------------------------------------------

typedef __hip_bfloat16 bf16;
typedef __attribute__((ext_vector_type(8))) short bf16x8;
typedef __attribute__((ext_vector_type(4))) short s16x4;
typedef __attribute__((ext_vector_type(4)))  float f32x4;
typedef __attribute__((ext_vector_type(16))) float f32x16;

__device__ __forceinline__ short f2bf(float f) {   // RNE f32->bf16
    unsigned u = __builtin_bit_cast(unsigned, f);
    return (short)((u + 0x7fffu + ((u >> 16) & 1u)) >> 16);
}

#define GLD_LDS(gaddr, laddr)                                                  \
    __builtin_amdgcn_global_load_lds(                                          \
        (const __attribute__((address_space(1))) void*)(gaddr),                \
        (__attribute__((address_space(3))) void*)(laddr), 16, 0, 0)

// ---------------- workspace layout (bytes) ----------------
#define OFF_GBF    0u
#define OFF_XRT0   25165824u
#define OFF_XRT1   26214400u
#define OFF_XS0T   27262976u
#define OFF_HS0T   27787264u
#define OFF_S0X    36175872u
#define OFF_S1S    36962304u
#define OFF_W0SW   74711040u
#define OFF_W1SW   79429632u
#define OFF_BIAS0  85721088u
#define OFF_BIAS1  85753856u
#define OFF_C0     85786624u
#define OFF_C1     87883776u
#define WS_NEEDED  89980928u

// ---------------------------------------------------------------------------
__global__ __launch_bounds__(256) void prep_kernel(
    const float* __restrict__ G, const float* __restrict__ x_seq,
    const float* __restrict__ init_h, const float* __restrict__ init_c,
    bf16* __restrict__ Gbf, bf16* __restrict__ XrT0, bf16* __restrict__ XrT1,
    bf16* __restrict__ Xs0T, float* __restrict__ c0, float* __restrict__ c1)
{
    const int SZ_G4 = 3145728;
    const int SZ_XR = 524288, SZ_XS = 262144, SZ_C = 524288;
    const int TOTAL = SZ_G4 + 2*SZ_XR + SZ_XS + 2*SZ_C;
    int stride = gridDim.x * 256;
    for (int idx = blockIdx.x*256 + threadIdx.x; idx < TOTAL; idx += stride) {
        int i0 = idx;
        if (i0 < SZ_G4) {
            f32x4 v = *((const f32x4*)G + i0);
            s16x4 o;
            #pragma unroll
            for (int e = 0; e < 4; e++) o[e] = f2bf(v[e]);
            *((s16x4*)Gbf + i0) = o;
            continue;
        }
        i0 -= SZ_G4;
        if (i0 < SZ_XR) {
            int n = i0 >> 11, j = i0 & 2047; int b = n >> 6, h = n & 63;
            XrT0[i0] = __float2bfloat16(init_h[((size_t)b*2048 + j)*64 + h]);
            continue;
        }
        i0 -= SZ_XR;
        if (i0 < SZ_XR) {
            int n = i0 >> 11, j = i0 & 2047; int b = n >> 6, h = n & 63;
            XrT1[i0] = __float2bfloat16(init_h[((size_t)(4+b)*2048 + j)*64 + h]);
            continue;
        }
        i0 -= SZ_XR;
        if (i0 < SZ_XS) {
            int n = i0 >> 11, j = i0 & 2047;
            float v = 0.f;
            if (n < 64) {
                int t = n >> 3, rm = n & 7, b = rm >> 1, cc = rm & 1;
                v = x_seq[(((size_t)b*8 + t)*2048 + j)*2 + cc];
            }
            Xs0T[i0] = __float2bfloat16(v);
            continue;
        }
        i0 -= SZ_XS;
        if (i0 < SZ_C) { c0[i0] = init_c[i0]; continue; }
        i0 -= SZ_C;
        c1[i0] = init_c[SZ_C + i0];
    }
}

// ---------------------------------------------------------------------------
__global__ __launch_bounds__(256) void metaw_kernel(
    const float* __restrict__ x_meta,
    const float* __restrict__ lw1_0, const float* __restrict__ lb1_0,
    const float* __restrict__ lw2_0, const float* __restrict__ lb2_0,
    const float* __restrict__ bw1_0, const float* __restrict__ bb1_0,
    const float* __restrict__ bw2_0, const float* __restrict__ bb2_0,
    const float* __restrict__ lw1_1, const float* __restrict__ lb1_1,
    const float* __restrict__ lw2_1, const float* __restrict__ lb2_1,
    const float* __restrict__ bw1_1, const float* __restrict__ bb1_1,
    const float* __restrict__ bw2_1, const float* __restrict__ bb2_1,
    bf16* __restrict__ W0sw, bf16* __restrict__ W1sw,
    float* __restrict__ bias0, float* __restrict__ bias1)
{
    int tid = threadIdx.x, bid = blockIdx.x;
    const float *w1, *b1v, *w2, *b2v;
    int task, r = 0;
    if (bid < 384)      { task = 0; r = bid;       w1=lw1_1; b1v=lb1_1; w2=lw2_1; b2v=lb2_1; }
    else if (bid < 582) { task = 1; r = bid - 384; w1=lw1_0; b1v=lb1_0; w2=lw2_0; b2v=lb2_0; }
    else if (bid == 582){ task = 2;                w1=bw1_0; b1v=bb1_0; w2=bw2_0; b2v=bb2_0; }
    else                { task = 3;                w1=bw1_1; b1v=bb1_1; w2=bw2_1; b2v=bb2_1; }

    __shared__ float hid[32][64];
    for (int idx = tid; idx < 2048; idx += 256) {
        int tb = idx >> 6, h = idx & 63;
        int tt = tb >> 2, b = tb & 3;
        float a = b1v[h];
        #pragma unroll
        for (int m = 0; m < 32; m++)
            a += x_meta[((size_t)b*8 + tt)*32 + m] * w1[m*64 + h];
        hid[tb][h] = fmaxf(a, 0.f);
    }
    __syncthreads();

    int o = tid;
    int RO = (task == 0) ? 98304 : (task == 1) ? 50688 : 256;
    int ro = (task >= 2) ? o : (r*256 + o);
    float col[64];
    #pragma unroll
    for (int h = 0; h < 64; h++) col[h] = w2[(size_t)h*RO + ro];
    float base = b2v[ro];

    for (int tb = 0; tb < 32; tb++) {
        float v = base;
        #pragma unroll
        for (int h = 0; h < 64; h++) v += hid[tb][h]*col[h];
        if (task == 0) {
            int rp = r, rc = rp >> 5, rr = rp & 31;
            int oc = o >> 4, l = ((rr >> 3) << 4) + (o & 15), e = rr & 7;
            W1sw[(((size_t)tb*12 + rc)*16 + oc)*512 + l*8 + e] = __float2bfloat16(v);
        } else if (task == 1) {
            int k = r/66, d = r - k*66;
            int rp = k*96 + (d < 2 ? 64 + d : d - 2);
            int rc = rp >> 5, rr = rp & 31;
            int oc = o >> 4, l = ((rr >> 3) << 4) + (o & 15), e = rr & 7;
            W0sw[(((size_t)tb*9 + rc)*16 + oc)*512 + l*8 + e] = __float2bfloat16(v);
        } else if (task == 2) bias0[tb*256 + o] = v;
        else                  bias1[tb*256 + o] = v;
    }
}

// ---------------------------------------------------------------------------
// gemm_tile<MODE>: unchanged from R2/R3 (proven).  MODE 1: S1s;  MODE 2: S0x.
// ---------------------------------------------------------------------------
template<int MODE>
__global__ __launch_bounds__(256) void gemm_tile(
    const short* __restrict__ A, const short* __restrict__ Bm,
    bf16* __restrict__ dstB)
{
    constexpr int NT  = (MODE == 1) ? 16 : 1;
    constexpr int NWG = 48 * NT;

    int bid  = blockIdx.x;
    int wgid = (bid & 7) * (NWG / 8) + (bid >> 3);
    int mt, nt;
    if (MODE == 1) { mt = wgid >> 4; nt = wgid & 15; }
    else           { mt = wgid; nt = 0; }

    int kk = mt >> 4;

    __shared__ short lA[128 * 64];
    __shared__ short lB[128 * 64];

    int tid = threadIdx.x, lane = tid & 63, w = tid >> 6;
    int wr = w >> 1, wc = w & 1;

    int rloc = lane >> 3;
    int gsrc = ((lane & 7) ^ rloc) * 8;
    const short* Ab = A  + (size_t)(mt * 128) * 2048 + gsrc;
    const short* Bb = Bm + (size_t)(nt * 128) * 2048 + gsrc;

    f32x4 acc[4][4];
    #pragma unroll
    for (int mf = 0; mf < 4; mf++)
        #pragma unroll
        for (int nf = 0; nf < 4; nf++)
            #pragma unroll
            for (int q = 0; q < 4; q++) acc[mf][nf][q] = 0.f;

    for (int kb = 0; kb < 2048; kb += 64) {
        #pragma unroll
        for (int q = 0; q < 4; q++) {
            int row = (w * 4 + q) * 8 + rloc;
            GLD_LDS(Ab + (size_t)row * 2048 + kb, &lA[(w * 4 + q) * 512]);
            GLD_LDS(Bb + (size_t)row * 2048 + kb, &lB[(w * 4 + q) * 512]);
        }
        __syncthreads();
        #pragma unroll
        for (int ks = 0; ks < 2; ks++) {
            bf16x8 af[4], bfr[4];
            #pragma unroll
            for (int mf = 0; mf < 4; mf++) {
                int r = wr * 64 + mf * 16 + (lane & 15);
                int cb = ((lane >> 4) * 16 + ks * 64) ^ ((r & 7) << 4);
                af[mf] = *(const bf16x8*)((const char*)lA + r * 128 + cb);
            }
            #pragma unroll
            for (int nf = 0; nf < 4; nf++) {
                int r = wc * 64 + nf * 16 + (lane & 15);
                int cb = ((lane >> 4) * 16 + ks * 64) ^ ((r & 7) << 4);
                bfr[nf] = *(const bf16x8*)((const char*)lB + r * 128 + cb);
            }
            #pragma unroll
            for (int mf = 0; mf < 4; mf++)
                #pragma unroll
                for (int nf = 0; nf < 4; nf++)
                    acc[mf][nf] = __builtin_amdgcn_mfma_f32_16x16x32_bf16(
                        af[mf], bfr[nf], acc[mf][nf], 0, 0, 0);
        }
        __syncthreads();
    }

    int l15 = lane & 15, lg4 = (lane >> 4) * 4;
    int ibase = (mt & 15) * 128 + wr * 64;
    #pragma unroll
    for (int mf = 0; mf < 4; mf++) {
        #pragma unroll
        for (int nf = 0; nf < 4; nf++) {
            int gn = nt * 128 + wc * 64 + nf * 16 + l15;
            #pragma unroll
            for (int reg = 0; reg < 4; reg++) {
                int gm = ibase + mf * 16 + lg4 + reg;
                float v = acc[mf][nf][reg];
                if (MODE == 1) {
                    int tt = gn >> 8, c = gn & 255;
                    dstB[(((size_t)tt * 3 + kk) * 2048 + gm) * 256 + c] = __float2bfloat16(v);
                } else {
                    if (gn < 64)
                        dstB[((size_t)kk * 2048 + gm) * 64 + gn] = __float2bfloat16(v);
                }
            }
        }
    }
}

// ---------------------------------------------------------------------------
// step_fused<LAYER>: one launch per time step.  R4: pipelined staging.
// Triple-buffered 40KB chunks, issue-ahead-2, one s_barrier + vmcnt(10)/iter.
// Each STAGE = exactly 10 global_load_lds per thread (6 G + 4 h).
// ---------------------------------------------------------------------------
template<int LAYER>
__global__ __launch_bounds__(256, 1) void step_fused(
    const short* __restrict__ Gbf, const short* __restrict__ Sstat,
    const short* __restrict__ Wsw, const float* __restrict__ bias,
    float* __restrict__ cbuf, bf16* __restrict__ xrT, bf16* __restrict__ hs0T,
    float* __restrict__ out, int t)
{
    constexpr int NC = (LAYER == 0) ? 9 : 12;
    // [0,122880): 3 staging buffers (lG 24KB + lH 16KB each, stride 40960)
    // [0, 98304): phase-2 f32 partials (aliased; used after staging done)
    // [122880,139264): sup_lds: 32 rows x 512 B, XOR-swizzled ((i&15)<<4)
    __shared__ char lds[139264];
    char* SUP = lds + 122880;

    int tid = threadIdx.x, lane = tid & 63, w = tid >> 6;
    int bid = blockIdx.x;
    int q = bid >> 3;
    int it = (bid & 7) * 8 + (q >> 2), b = q & 3;
    int i0 = it * 32;
    int l31 = lane & 31, eo = lane >> 5, l15 = lane & 15, lg = lane >> 4;

    const short* xr = (const short*)xrT;

    f32x16 acc6[6];
    #pragma unroll
    for (int f = 0; f < 6; f++)
        #pragma unroll
        for (int r = 0; r < 16; r++) acc6[f][r] = 0.f;

    auto STAGE = [&](int bufi, int jb) {
        char* base = lds + bufi * 40960;
        #pragma unroll
        for (int qq = 0; qq < 6; qq++) {           // G: 3x32 rows x 128 j
            int g = tid + qq * 256;
            int kr = g >> 4, p = g & 15;
            int k = kr >> 5, row = kr & 31;
            const short* src = Gbf + ((size_t)(k * 2048 + i0 + row)) * 2048
                               + jb + ((p ^ (row & 15)) * 8);
            GLD_LDS(src, base + g * 16);
        }
        char* hbase = base + 24576;
        #pragma unroll
        for (int qq = 0; qq < 4; qq++) {           // h^T: 64 d-rows x 128 j
            int g = tid + qq * 256;
            int d = g >> 4, p = g & 15;
            const short* src = xr + ((size_t)(b * 64 + d)) * 2048
                               + jb + ((p ^ (d & 15)) * 8);
            GLD_LDS(src, hbase + g * 16);
        }
    };

    auto COMPUTE = [&](int bufi) {
        char* base = lds + bufi * 40960;
        char* hbase = base + 24576;
        #pragma unroll
        for (int ks = 0; ks < 2; ks++) {
            int jl2 = w * 64 + ks * 32 + eo * 16;
            bf16x8 a[3], bb[2];
            #pragma unroll
            for (int k = 0; k < 3; k++)
                a[k] = *(const bf16x8*)(base + k * 8192 + l31 * 256
                                        + (jl2 ^ ((l31 & 15) << 4)));
            #pragma unroll
            for (int dc = 0; dc < 2; dc++) {
                int d = dc * 32 + l31;
                bb[dc] = *(const bf16x8*)(hbase + d * 256 + (jl2 ^ ((d & 15) << 4)));
            }
            #pragma unroll
            for (int k = 0; k < 3; k++)
                #pragma unroll
                for (int dc = 0; dc < 2; dc++)
                    acc6[k * 2 + dc] = __builtin_amdgcn_mfma_f32_32x32x16_bf16(
                        a[k], bb[dc], acc6[k * 2 + dc], 0, 0, 0);
        }
    };

    // ---- pipelined main loop: 16 chunks of 128 j ----
    STAGE(0, 0);
    STAGE(1, 128);
    asm volatile("s_waitcnt vmcnt(10)" ::: "memory");   // buf0 landed (buf1 in flight)
    __builtin_amdgcn_s_barrier();

    int sbuf = 2, cb = 0;
    #pragma unroll 1
    for (int m = 0; m < 16; m++) {
        if (m < 14) STAGE(sbuf, (m + 2) * 128);
        COMPUTE(cb);
        if (m < 14)       asm volatile("s_waitcnt vmcnt(10)" ::: "memory");
        else if (m == 14) asm volatile("s_waitcnt vmcnt(0)"  ::: "memory");
        __builtin_amdgcn_s_barrier();
        sbuf = (sbuf == 2) ? 0 : sbuf + 1;
        cb   = (cb   == 2) ? 0 : cb + 1;
    }

    // phase 2a: write per-wave f32 partials (overwrites staging region)
    #pragma unroll
    for (int f = 0; f < 6; f++) {
        float* pb = (float*)(lds + (size_t)(w * 6 + f) * 4096) + lane * 16;
        #pragma unroll
        for (int qq = 0; qq < 4; qq++) {
            f32x4 v;
            #pragma unroll
            for (int r = 0; r < 4; r++) v[r] = acc6[f][qq * 4 + r];
            *(f32x4*)(pb + qq * 4) = v;
        }
    }
    __syncthreads();

    // phase 2b: reduce 4 partials -> bf16 sup_lds (swizzled)
    #pragma unroll
    for (int c2 = 0; c2 < 6; c2++) {
        int cid = c2 * 256 + tid;
        int f = cid >> 8, p0 = (cid & 255) * 4;
        f32x4 s = *(const f32x4*)(lds + (size_t)f * 4096 + p0 * 4);
        #pragma unroll
        for (int ww = 1; ww < 4; ww++) {
            f32x4 v = *(const f32x4*)(lds + (size_t)(ww * 6 + f) * 4096 + p0 * 4);
            s[0] += v[0]; s[1] += v[1]; s[2] += v[2]; s[3] += v[3];
        }
        int k = f >> 1, dc = f & 1;
        int col = (p0 >> 4) & 31, hi = p0 >> 9, r0 = p0 & 15;
        int ib = (r0 >> 2) * 8 + hi * 4;
        int dp = k * 64 + dc * 32 + col;
        #pragma unroll
        for (int u = 0; u < 4; u++) {
            int i = ib + u;
            *(short*)(SUP + i * 512 + ((dp * 2) ^ ((i & 15) << 4))) = f2bf(s[u]);
        }
    }
    __syncthreads();

    // phase 3: gemm2 (gates = sup @ W + bias) + LSTM
    f32x4 ag[2][4];
    #pragma unroll
    for (int mi = 0; mi < 2; mi++)
        #pragma unroll
        for (int g = 0; g < 4; g++)
            #pragma unroll
            for (int r = 0; r < 4; r++) ag[mi][g][r] = 0.f;

    const short* WswT = Wsw + (size_t)(t * 4 + b) * NC * 16 * 512;

    #pragma unroll
    for (int rc = 0; rc < NC; rc++) {
        bf16x8 a0, a1;
        if (LAYER == 1) {
            int kk = rc >> 2, dq = rc & 3;
            if (dq < 2) {
                const short* src = Sstat + (size_t)t * 3 * 2048 * 256;
                int col = b * 64 + dq * 32 + lg * 8;
                a0 = *(const bf16x8*)(src + ((size_t)kk * 2048 + i0 + l15) * 256 + col);
                a1 = *(const bf16x8*)(src + ((size_t)kk * 2048 + i0 + 16 + l15) * 256 + col);
            } else {
                int dpb = (kk * 64 + (dq - 2) * 32 + lg * 8) * 2;
                a0 = *(const bf16x8*)(SUP + l15 * 512 + (dpb ^ (l15 << 4)));
                a1 = *(const bf16x8*)(SUP + (l15 + 16) * 512 + (dpb ^ (l15 << 4)));
            }
        } else {
            int kk = rc / 3, dd = rc - kk * 3;
            if (dd < 2) {
                int dpb = (kk * 64 + dd * 32 + lg * 8) * 2;
                a0 = *(const bf16x8*)(SUP + l15 * 512 + (dpb ^ (l15 << 4)));
                a1 = *(const bf16x8*)(SUP + (l15 + 16) * 512 + (dpb ^ (l15 << 4)));
            } else {
                #pragma unroll
                for (int e = 0; e < 8; e++) { a0[e] = 0; a1[e] = 0; }
                if (lg == 0) {
                    unsigned v0 = *(const unsigned*)(Sstat + ((size_t)kk * 2048 + i0 + l15) * 64 + t * 8 + b * 2);
                    unsigned v1 = *(const unsigned*)(Sstat + ((size_t)kk * 2048 + i0 + 16 + l15) * 64 + t * 8 + b * 2);
                    a0[0] = (short)(v0 & 0xffff); a0[1] = (short)(v0 >> 16);
                    a1[0] = (short)(v1 & 0xffff); a1[1] = (short)(v1 >> 16);
                }
            }
        }
        #pragma unroll
        for (int g = 0; g < 4; g++) {
            bf16x8 wf = *(const bf16x8*)(WswT + (((size_t)rc * 16 + (g * 4 + w)) * 64 + lane) * 8);
            ag[0][g] = __builtin_amdgcn_mfma_f32_16x16x32_bf16(a0, wf, ag[0][g], 0, 0, 0);
            ag[1][g] = __builtin_amdgcn_mfma_f32_16x16x32_bf16(a1, wf, ag[1][g], 0, 0, 0);
        }
    }

    int hcol = w * 16 + l15;
    float bia[4];
    #pragma unroll
    for (int g = 0; g < 4; g++) bia[g] = bias[(t * 4 + b) * 256 + g * 64 + hcol];

    #pragma unroll
    for (int mi = 0; mi < 2; mi++) {
        #pragma unroll
        for (int r = 0; r < 4; r++) {
            int i = i0 + mi * 16 + lg * 4 + r;
            float gi = ag[mi][0][r] + bia[0];
            float gf = ag[mi][1][r] + bia[1];
            float go = ag[mi][2][r] + bia[2];
            float gg = ag[mi][3][r] + bia[3];
            size_t cidx = ((size_t)b * 2048 + i) * 64 + hcol;
            float c_old = cbuf[cidx];
            float si = 1.f / (1.f + __expf(-gi));
            float sf = 1.f / (1.f + __expf(-gf));
            float so = 1.f / (1.f + __expf(-go));
            float cn = sf * c_old + si * tanhf(gg);
            float hn = so * tanhf(cn);
            cbuf[cidx] = cn;
            bf16 hb = __float2bfloat16(hn);
            xrT[((size_t)b * 64 + hcol) * 2048 + i] = hb;
            if (LAYER == 0)
                hs0T[((size_t)t * 256 + b * 64 + hcol) * 2048 + i] = hb;
            if (t == 7) {
                out[(((size_t)LAYER * 4 + b) * 2048 + i) * 64 + hcol]       = hn;
                out[(((size_t)(2 + LAYER) * 4 + b) * 2048 + i) * 64 + hcol] = cn;
            }
        }
    }
}

// ---------------------------------------------------------------------------
extern "C" void kernel_launch(void* const* d_in, const int* in_sizes, int n_in,
                              void* d_out, int out_size, void* d_ws, size_t ws_size,
                              hipStream_t stream)
{
    const float* G      = (const float*)d_in[0];
    const float* x_seq  = (const float*)d_in[1];
    const float* init_h = (const float*)d_in[2];
    const float* init_c = (const float*)d_in[3];
    const float* x_meta = (const float*)d_in[4];
    const float* lw1_0 = (const float*)d_in[5],  *lb1_0 = (const float*)d_in[6];
    const float* lw2_0 = (const float*)d_in[7],  *lb2_0 = (const float*)d_in[8];
    const float* bw1_0 = (const float*)d_in[9],  *bb1_0 = (const float*)d_in[10];
    const float* bw2_0 = (const float*)d_in[11], *bb2_0 = (const float*)d_in[12];
    const float* lw1_1 = (const float*)d_in[13], *lb1_1 = (const float*)d_in[14];
    const float* lw2_1 = (const float*)d_in[15], *lb2_1 = (const float*)d_in[16];
    const float* bw1_1 = (const float*)d_in[17], *bb1_1 = (const float*)d_in[18];
    const float* bw2_1 = (const float*)d_in[19], *bb2_1 = (const float*)d_in[20];

    if (ws_size < WS_NEEDED) return;

    char* ws = (char*)d_ws;
    bf16*  Gbf   = (bf16*) (ws + OFF_GBF);
    bf16*  XrT0  = (bf16*) (ws + OFF_XRT0);
    bf16*  XrT1  = (bf16*) (ws + OFF_XRT1);
    bf16*  Xs0T  = (bf16*) (ws + OFF_XS0T);
    bf16*  hs0T  = (bf16*) (ws + OFF_HS0T);
    bf16*  S0x   = (bf16*) (ws + OFF_S0X);
    bf16*  S1s   = (bf16*) (ws + OFF_S1S);
    bf16*  W0sw  = (bf16*) (ws + OFF_W0SW);
    bf16*  W1sw  = (bf16*) (ws + OFF_W1SW);
    float* bias0 = (float*)(ws + OFF_BIAS0);
    float* bias1 = (float*)(ws + OFF_BIAS1);
    float* c0    = (float*)(ws + OFF_C0);
    float* c1    = (float*)(ws + OFF_C1);
    float* out   = (float*)d_out;

    prep_kernel<<<4096, 256, 0, stream>>>(G, x_seq, init_h, init_c,
                                          Gbf, XrT0, XrT1, Xs0T, c0, c1);
    metaw_kernel<<<584, 256, 0, stream>>>(x_meta,
        lw1_0, lb1_0, lw2_0, lb2_0, bw1_0, bb1_0, bw2_0, bb2_0,
        lw1_1, lb1_1, lw2_1, lb2_1, bw1_1, bb1_1, bw2_1, bb2_1,
        W0sw, W1sw, bias0, bias1);

    gemm_tile<2><<<48, 256, 0, stream>>>((const short*)Gbf, (const short*)Xs0T, S0x);

    for (int t = 0; t < 8; t++)
        step_fused<0><<<256, 256, 0, stream>>>((const short*)Gbf, (const short*)S0x,
            (const short*)W0sw, bias0, c0, XrT0, hs0T, out, t);

    gemm_tile<1><<<768, 256, 0, stream>>>((const short*)Gbf, (const short*)hs0T, S1s);

    for (int t = 0; t < 8; t++)
        step_fused<1><<<256, 256, 0, stream>>>((const short*)Gbf, (const short*)S1s,
            (const short*)W1sw, bias1, c1, XrT1, nullptr, out, t);
}

// Round 5
// 534.196 us; speedup vs baseline: 2.3703x; 1.0272x over previous
//
#include <hip/hip_runtime.h>
#include <hip/hip_bf16.h>
#include <cstdint>

// ---------------------------------------------------------------------------
// Meta-GCN LSTM encoder.  L=2, B=4, T=8, N=2048, C=2, H=64, K=3, M=32.
// R5: epilogue h-writes (xrT, hs0T) were 2-byte/4KB-stride scatters (64 cache
// lines per store instr).  Now staged through a 4KB LDS tile and written as
// coalesced 16B/lane global_store_dwordx4.  All else identical to R4.
// ---------------------------------------------------------------------------

typedef __hip_bfloat16 bf16;
typedef __attribute__((ext_vector_type(8))) short bf16x8;
typedef __attribute__((ext_vector_type(4))) short s16x4;
typedef __attribute__((ext_vector_type(4)))  float f32x4;
typedef __attribute__((ext_vector_type(16))) float f32x16;

__device__ __forceinline__ short f2bf(float f) {   // RNE f32->bf16
    unsigned u = __builtin_bit_cast(unsigned, f);
    return (short)((u + 0x7fffu + ((u >> 16) & 1u)) >> 16);
}

#define GLD_LDS(gaddr, laddr)                                                  \
    __builtin_amdgcn_global_load_lds(                                          \
        (const __attribute__((address_space(1))) void*)(gaddr),                \
        (__attribute__((address_space(3))) void*)(laddr), 16, 0, 0)

// ---------------- workspace layout (bytes) ----------------
#define OFF_GBF    0u
#define OFF_XRT0   25165824u
#define OFF_XRT1   26214400u
#define OFF_XS0T   27262976u
#define OFF_HS0T   27787264u
#define OFF_S0X    36175872u
#define OFF_S1S    36962304u
#define OFF_W0SW   74711040u
#define OFF_W1SW   79429632u
#define OFF_BIAS0  85721088u
#define OFF_BIAS1  85753856u
#define OFF_C0     85786624u
#define OFF_C1     87883776u
#define WS_NEEDED  89980928u

// ---------------------------------------------------------------------------
__global__ __launch_bounds__(256) void prep_kernel(
    const float* __restrict__ G, const float* __restrict__ x_seq,
    const float* __restrict__ init_h, const float* __restrict__ init_c,
    bf16* __restrict__ Gbf, bf16* __restrict__ XrT0, bf16* __restrict__ XrT1,
    bf16* __restrict__ Xs0T, float* __restrict__ c0, float* __restrict__ c1)
{
    const int SZ_G4 = 3145728;
    const int SZ_XR = 524288, SZ_XS = 262144, SZ_C = 524288;
    const int TOTAL = SZ_G4 + 2*SZ_XR + SZ_XS + 2*SZ_C;
    int stride = gridDim.x * 256;
    for (int idx = blockIdx.x*256 + threadIdx.x; idx < TOTAL; idx += stride) {
        int i0 = idx;
        if (i0 < SZ_G4) {
            f32x4 v = *((const f32x4*)G + i0);
            s16x4 o;
            #pragma unroll
            for (int e = 0; e < 4; e++) o[e] = f2bf(v[e]);
            *((s16x4*)Gbf + i0) = o;
            continue;
        }
        i0 -= SZ_G4;
        if (i0 < SZ_XR) {
            int n = i0 >> 11, j = i0 & 2047; int b = n >> 6, h = n & 63;
            XrT0[i0] = __float2bfloat16(init_h[((size_t)b*2048 + j)*64 + h]);
            continue;
        }
        i0 -= SZ_XR;
        if (i0 < SZ_XR) {
            int n = i0 >> 11, j = i0 & 2047; int b = n >> 6, h = n & 63;
            XrT1[i0] = __float2bfloat16(init_h[((size_t)(4+b)*2048 + j)*64 + h]);
            continue;
        }
        i0 -= SZ_XR;
        if (i0 < SZ_XS) {
            int n = i0 >> 11, j = i0 & 2047;
            float v = 0.f;
            if (n < 64) {
                int t = n >> 3, rm = n & 7, b = rm >> 1, cc = rm & 1;
                v = x_seq[(((size_t)b*8 + t)*2048 + j)*2 + cc];
            }
            Xs0T[i0] = __float2bfloat16(v);
            continue;
        }
        i0 -= SZ_XS;
        if (i0 < SZ_C) { c0[i0] = init_c[i0]; continue; }
        i0 -= SZ_C;
        c1[i0] = init_c[SZ_C + i0];
    }
}

// ---------------------------------------------------------------------------
__global__ __launch_bounds__(256) void metaw_kernel(
    const float* __restrict__ x_meta,
    const float* __restrict__ lw1_0, const float* __restrict__ lb1_0,
    const float* __restrict__ lw2_0, const float* __restrict__ lb2_0,
    const float* __restrict__ bw1_0, const float* __restrict__ bb1_0,
    const float* __restrict__ bw2_0, const float* __restrict__ bb2_0,
    const float* __restrict__ lw1_1, const float* __restrict__ lb1_1,
    const float* __restrict__ lw2_1, const float* __restrict__ lb2_1,
    const float* __restrict__ bw1_1, const float* __restrict__ bb1_1,
    const float* __restrict__ bw2_1, const float* __restrict__ bb2_1,
    bf16* __restrict__ W0sw, bf16* __restrict__ W1sw,
    float* __restrict__ bias0, float* __restrict__ bias1)
{
    int tid = threadIdx.x, bid = blockIdx.x;
    const float *w1, *b1v, *w2, *b2v;
    int task, r = 0;
    if (bid < 384)      { task = 0; r = bid;       w1=lw1_1; b1v=lb1_1; w2=lw2_1; b2v=lb2_1; }
    else if (bid < 582) { task = 1; r = bid - 384; w1=lw1_0; b1v=lb1_0; w2=lw2_0; b2v=lb2_0; }
    else if (bid == 582){ task = 2;                w1=bw1_0; b1v=bb1_0; w2=bw2_0; b2v=bb2_0; }
    else                { task = 3;                w1=bw1_1; b1v=bb1_1; w2=bw2_1; b2v=bb2_1; }

    __shared__ float hid[32][64];
    for (int idx = tid; idx < 2048; idx += 256) {
        int tb = idx >> 6, h = idx & 63;
        int tt = tb >> 2, b = tb & 3;
        float a = b1v[h];
        #pragma unroll
        for (int m = 0; m < 32; m++)
            a += x_meta[((size_t)b*8 + tt)*32 + m] * w1[m*64 + h];
        hid[tb][h] = fmaxf(a, 0.f);
    }
    __syncthreads();

    int o = tid;
    int RO = (task == 0) ? 98304 : (task == 1) ? 50688 : 256;
    int ro = (task >= 2) ? o : (r*256 + o);
    float col[64];
    #pragma unroll
    for (int h = 0; h < 64; h++) col[h] = w2[(size_t)h*RO + ro];
    float base = b2v[ro];

    for (int tb = 0; tb < 32; tb++) {
        float v = base;
        #pragma unroll
        for (int h = 0; h < 64; h++) v += hid[tb][h]*col[h];
        if (task == 0) {
            int rp = r, rc = rp >> 5, rr = rp & 31;
            int oc = o >> 4, l = ((rr >> 3) << 4) + (o & 15), e = rr & 7;
            W1sw[(((size_t)tb*12 + rc)*16 + oc)*512 + l*8 + e] = __float2bfloat16(v);
        } else if (task == 1) {
            int k = r/66, d = r - k*66;
            int rp = k*96 + (d < 2 ? 64 + d : d - 2);
            int rc = rp >> 5, rr = rp & 31;
            int oc = o >> 4, l = ((rr >> 3) << 4) + (o & 15), e = rr & 7;
            W0sw[(((size_t)tb*9 + rc)*16 + oc)*512 + l*8 + e] = __float2bfloat16(v);
        } else if (task == 2) bias0[tb*256 + o] = v;
        else                  bias1[tb*256 + o] = v;
    }
}

// ---------------------------------------------------------------------------
// gemm_tile<MODE>: unchanged (proven).  MODE 1: S1s;  MODE 2: S0x.
// ---------------------------------------------------------------------------
template<int MODE>
__global__ __launch_bounds__(256) void gemm_tile(
    const short* __restrict__ A, const short* __restrict__ Bm,
    bf16* __restrict__ dstB)
{
    constexpr int NT  = (MODE == 1) ? 16 : 1;
    constexpr int NWG = 48 * NT;

    int bid  = blockIdx.x;
    int wgid = (bid & 7) * (NWG / 8) + (bid >> 3);
    int mt, nt;
    if (MODE == 1) { mt = wgid >> 4; nt = wgid & 15; }
    else           { mt = wgid; nt = 0; }

    int kk = mt >> 4;

    __shared__ short lA[128 * 64];
    __shared__ short lB[128 * 64];

    int tid = threadIdx.x, lane = tid & 63, w = tid >> 6;
    int wr = w >> 1, wc = w & 1;

    int rloc = lane >> 3;
    int gsrc = ((lane & 7) ^ rloc) * 8;
    const short* Ab = A  + (size_t)(mt * 128) * 2048 + gsrc;
    const short* Bb = Bm + (size_t)(nt * 128) * 2048 + gsrc;

    f32x4 acc[4][4];
    #pragma unroll
    for (int mf = 0; mf < 4; mf++)
        #pragma unroll
        for (int nf = 0; nf < 4; nf++)
            #pragma unroll
            for (int q = 0; q < 4; q++) acc[mf][nf][q] = 0.f;

    for (int kb = 0; kb < 2048; kb += 64) {
        #pragma unroll
        for (int q = 0; q < 4; q++) {
            int row = (w * 4 + q) * 8 + rloc;
            GLD_LDS(Ab + (size_t)row * 2048 + kb, &lA[(w * 4 + q) * 512]);
            GLD_LDS(Bb + (size_t)row * 2048 + kb, &lB[(w * 4 + q) * 512]);
        }
        __syncthreads();
        #pragma unroll
        for (int ks = 0; ks < 2; ks++) {
            bf16x8 af[4], bfr[4];
            #pragma unroll
            for (int mf = 0; mf < 4; mf++) {
                int r = wr * 64 + mf * 16 + (lane & 15);
                int cb = ((lane >> 4) * 16 + ks * 64) ^ ((r & 7) << 4);
                af[mf] = *(const bf16x8*)((const char*)lA + r * 128 + cb);
            }
            #pragma unroll
            for (int nf = 0; nf < 4; nf++) {
                int r = wc * 64 + nf * 16 + (lane & 15);
                int cb = ((lane >> 4) * 16 + ks * 64) ^ ((r & 7) << 4);
                bfr[nf] = *(const bf16x8*)((const char*)lB + r * 128 + cb);
            }
            #pragma unroll
            for (int mf = 0; mf < 4; mf++)
                #pragma unroll
                for (int nf = 0; nf < 4; nf++)
                    acc[mf][nf] = __builtin_amdgcn_mfma_f32_16x16x32_bf16(
                        af[mf], bfr[nf], acc[mf][nf], 0, 0, 0);
        }
        __syncthreads();
    }

    int l15 = lane & 15, lg4 = (lane >> 4) * 4;
    int ibase = (mt & 15) * 128 + wr * 64;
    #pragma unroll
    for (int mf = 0; mf < 4; mf++) {
        #pragma unroll
        for (int nf = 0; nf < 4; nf++) {
            int gn = nt * 128 + wc * 64 + nf * 16 + l15;
            #pragma unroll
            for (int reg = 0; reg < 4; reg++) {
                int gm = ibase + mf * 16 + lg4 + reg;
                float v = acc[mf][nf][reg];
                if (MODE == 1) {
                    int tt = gn >> 8, c = gn & 255;
                    dstB[(((size_t)tt * 3 + kk) * 2048 + gm) * 256 + c] = __float2bfloat16(v);
                } else {
                    if (gn < 64)
                        dstB[((size_t)kk * 2048 + gm) * 64 + gn] = __float2bfloat16(v);
                }
            }
        }
    }
}

// ---------------------------------------------------------------------------
// step_fused<LAYER>: one launch per time step.  R5: coalesced h write-out.
// ---------------------------------------------------------------------------
template<int LAYER>
__global__ __launch_bounds__(256, 1) void step_fused(
    const short* __restrict__ Gbf, const short* __restrict__ Sstat,
    const short* __restrict__ Wsw, const float* __restrict__ bias,
    float* __restrict__ cbuf, bf16* __restrict__ xrT, bf16* __restrict__ hs0T,
    float* __restrict__ out, int t)
{
    constexpr int NC = (LAYER == 0) ? 9 : 12;
    // [0,122880): 3 staging buffers (stride 40960); aliased: phase-2 partials,
    //             epilogue hT tile (4KB)
    // [122880,139264): sup_lds: 32 rows x 512 B, XOR-swizzled
    __shared__ char lds[139264];
    char* SUP = lds + 122880;

    int tid = threadIdx.x, lane = tid & 63, w = tid >> 6;
    int bid = blockIdx.x;
    int q = bid >> 3;
    int it = (bid & 7) * 8 + (q >> 2), b = q & 3;
    int i0 = it * 32;
    int l31 = lane & 31, eo = lane >> 5, l15 = lane & 15, lg = lane >> 4;

    const short* xr = (const short*)xrT;

    f32x16 acc6[6];
    #pragma unroll
    for (int f = 0; f < 6; f++)
        #pragma unroll
        for (int r = 0; r < 16; r++) acc6[f][r] = 0.f;

    auto STAGE = [&](int bufi, int jb) {
        char* base = lds + bufi * 40960;
        #pragma unroll
        for (int qq = 0; qq < 6; qq++) {           // G: 3x32 rows x 128 j
            int g = tid + qq * 256;
            int kr = g >> 4, p = g & 15;
            int k = kr >> 5, row = kr & 31;
            const short* src = Gbf + ((size_t)(k * 2048 + i0 + row)) * 2048
                               + jb + ((p ^ (row & 15)) * 8);
            GLD_LDS(src, base + g * 16);
        }
        char* hbase = base + 24576;
        #pragma unroll
        for (int qq = 0; qq < 4; qq++) {           // h^T: 64 d-rows x 128 j
            int g = tid + qq * 256;
            int d = g >> 4, p = g & 15;
            const short* src = xr + ((size_t)(b * 64 + d)) * 2048
                               + jb + ((p ^ (d & 15)) * 8);
            GLD_LDS(src, hbase + g * 16);
        }
    };

    auto COMPUTE = [&](int bufi) {
        char* base = lds + bufi * 40960;
        char* hbase = base + 24576;
        #pragma unroll
        for (int ks = 0; ks < 2; ks++) {
            int jl2 = w * 64 + ks * 32 + eo * 16;
            bf16x8 a[3], bb[2];
            #pragma unroll
            for (int k = 0; k < 3; k++)
                a[k] = *(const bf16x8*)(base + k * 8192 + l31 * 256
                                        + (jl2 ^ ((l31 & 15) << 4)));
            #pragma unroll
            for (int dc = 0; dc < 2; dc++) {
                int d = dc * 32 + l31;
                bb[dc] = *(const bf16x8*)(hbase + d * 256 + (jl2 ^ ((d & 15) << 4)));
            }
            #pragma unroll
            for (int k = 0; k < 3; k++)
                #pragma unroll
                for (int dc = 0; dc < 2; dc++)
                    acc6[k * 2 + dc] = __builtin_amdgcn_mfma_f32_32x32x16_bf16(
                        a[k], bb[dc], acc6[k * 2 + dc], 0, 0, 0);
        }
    };

    // ---- pipelined main loop: 16 chunks of 128 j ----
    STAGE(0, 0);
    STAGE(1, 128);
    asm volatile("s_waitcnt vmcnt(10)" ::: "memory");
    __builtin_amdgcn_s_barrier();

    int sbuf = 2, cb = 0;
    #pragma unroll 1
    for (int m = 0; m < 16; m++) {
        if (m < 14) STAGE(sbuf, (m + 2) * 128);
        COMPUTE(cb);
        if (m < 14)       asm volatile("s_waitcnt vmcnt(10)" ::: "memory");
        else if (m == 14) asm volatile("s_waitcnt vmcnt(0)"  ::: "memory");
        __builtin_amdgcn_s_barrier();
        sbuf = (sbuf == 2) ? 0 : sbuf + 1;
        cb   = (cb   == 2) ? 0 : cb + 1;
    }

    // phase 2a: write per-wave f32 partials (overwrites staging region)
    #pragma unroll
    for (int f = 0; f < 6; f++) {
        float* pb = (float*)(lds + (size_t)(w * 6 + f) * 4096) + lane * 16;
        #pragma unroll
        for (int qq = 0; qq < 4; qq++) {
            f32x4 v;
            #pragma unroll
            for (int r = 0; r < 4; r++) v[r] = acc6[f][qq * 4 + r];
            *(f32x4*)(pb + qq * 4) = v;
        }
    }
    __syncthreads();

    // phase 2b: reduce 4 partials -> bf16 sup_lds (swizzled)
    #pragma unroll
    for (int c2 = 0; c2 < 6; c2++) {
        int cid = c2 * 256 + tid;
        int f = cid >> 8, p0 = (cid & 255) * 4;
        f32x4 s = *(const f32x4*)(lds + (size_t)f * 4096 + p0 * 4);
        #pragma unroll
        for (int ww = 1; ww < 4; ww++) {
            f32x4 v = *(const f32x4*)(lds + (size_t)(ww * 6 + f) * 4096 + p0 * 4);
            s[0] += v[0]; s[1] += v[1]; s[2] += v[2]; s[3] += v[3];
        }
        int k = f >> 1, dc = f & 1;
        int col = (p0 >> 4) & 31, hi = p0 >> 9, r0 = p0 & 15;
        int ib = (r0 >> 2) * 8 + hi * 4;
        int dp = k * 64 + dc * 32 + col;
        #pragma unroll
        for (int u = 0; u < 4; u++) {
            int i = ib + u;
            *(short*)(SUP + i * 512 + ((dp * 2) ^ ((i & 15) << 4))) = f2bf(s[u]);
        }
    }
    __syncthreads();

    // phase 3: gemm2 (gates = sup @ W + bias) + LSTM
    f32x4 ag[2][4];
    #pragma unroll
    for (int mi = 0; mi < 2; mi++)
        #pragma unroll
        for (int g = 0; g < 4; g++)
            #pragma unroll
            for (int r = 0; r < 4; r++) ag[mi][g][r] = 0.f;

    const short* WswT = Wsw + (size_t)(t * 4 + b) * NC * 16 * 512;

    #pragma unroll
    for (int rc = 0; rc < NC; rc++) {
        bf16x8 a0, a1;
        if (LAYER == 1) {
            int kk = rc >> 2, dq = rc & 3;
            if (dq < 2) {
                const short* src = Sstat + (size_t)t * 3 * 2048 * 256;
                int col = b * 64 + dq * 32 + lg * 8;
                a0 = *(const bf16x8*)(src + ((size_t)kk * 2048 + i0 + l15) * 256 + col);
                a1 = *(const bf16x8*)(src + ((size_t)kk * 2048 + i0 + 16 + l15) * 256 + col);
            } else {
                int dpb = (kk * 64 + (dq - 2) * 32 + lg * 8) * 2;
                a0 = *(const bf16x8*)(SUP + l15 * 512 + (dpb ^ (l15 << 4)));
                a1 = *(const bf16x8*)(SUP + (l15 + 16) * 512 + (dpb ^ (l15 << 4)));
            }
        } else {
            int kk = rc / 3, dd = rc - kk * 3;
            if (dd < 2) {
                int dpb = (kk * 64 + dd * 32 + lg * 8) * 2;
                a0 = *(const bf16x8*)(SUP + l15 * 512 + (dpb ^ (l15 << 4)));
                a1 = *(const bf16x8*)(SUP + (l15 + 16) * 512 + (dpb ^ (l15 << 4)));
            } else {
                #pragma unroll
                for (int e = 0; e < 8; e++) { a0[e] = 0; a1[e] = 0; }
                if (lg == 0) {
                    unsigned v0 = *(const unsigned*)(Sstat + ((size_t)kk * 2048 + i0 + l15) * 64 + t * 8 + b * 2);
                    unsigned v1 = *(const unsigned*)(Sstat + ((size_t)kk * 2048 + i0 + 16 + l15) * 64 + t * 8 + b * 2);
                    a0[0] = (short)(v0 & 0xffff); a0[1] = (short)(v0 >> 16);
                    a1[0] = (short)(v1 & 0xffff); a1[1] = (short)(v1 >> 16);
                }
            }
        }
        #pragma unroll
        for (int g = 0; g < 4; g++) {
            bf16x8 wf = *(const bf16x8*)(WswT + (((size_t)rc * 16 + (g * 4 + w)) * 64 + lane) * 8);
            ag[0][g] = __builtin_amdgcn_mfma_f32_16x16x32_bf16(a0, wf, ag[0][g], 0, 0, 0);
            ag[1][g] = __builtin_amdgcn_mfma_f32_16x16x32_bf16(a1, wf, ag[1][g], 0, 0, 0);
        }
    }

    int hcol = w * 16 + l15;
    float bia[4];
    #pragma unroll
    for (int g = 0; g < 4; g++) bia[g] = bias[(t * 4 + b) * 256 + g * 64 + hcol];

    // epilogue: LSTM update; h staged into LDS tile hT[iloc(32)][hcol(64)]
    short* hT = (short*)lds;           // 4 KB, staging region is dead now
    #pragma unroll
    for (int mi = 0; mi < 2; mi++) {
        #pragma unroll
        for (int r = 0; r < 4; r++) {
            int iloc = mi * 16 + lg * 4 + r;
            int i = i0 + iloc;
            float gi = ag[mi][0][r] + bia[0];
            float gf = ag[mi][1][r] + bia[1];
            float go = ag[mi][2][r] + bia[2];
            float gg = ag[mi][3][r] + bia[3];
            size_t cidx = ((size_t)b * 2048 + i) * 64 + hcol;
            float c_old = cbuf[cidx];
            float si = 1.f / (1.f + __expf(-gi));
            float sf = 1.f / (1.f + __expf(-gf));
            float so = 1.f / (1.f + __expf(-go));
            float cn = sf * c_old + si * tanhf(gg);
            float hn = so * tanhf(cn);
            cbuf[cidx] = cn;
            hT[iloc * 64 + hcol] = f2bf(hn);
            if (t == 7) {
                out[(((size_t)LAYER * 4 + b) * 2048 + i) * 64 + hcol]       = hn;
                out[(((size_t)(2 + LAYER) * 4 + b) * 2048 + i) * 64 + hcol] = cn;
            }
        }
    }
    __syncthreads();

    // coalesced transposed write-out: row = hcol (64), seg = 8-i chunk (4)
    {
        int row = tid >> 2, seg = tid & 3;
        bf16x8 v;
        #pragma unroll
        for (int u = 0; u < 8; u++) v[u] = hT[(seg * 8 + u) * 64 + row];
        short* dst0 = (short*)xrT + ((size_t)b * 64 + row) * 2048 + i0 + seg * 8;
        *(bf16x8*)dst0 = v;
        if (LAYER == 0) {
            short* dst1 = (short*)hs0T + ((size_t)t * 256 + b * 64 + row) * 2048 + i0 + seg * 8;
            *(bf16x8*)dst1 = v;
        }
    }
}

// ---------------------------------------------------------------------------
extern "C" void kernel_launch(void* const* d_in, const int* in_sizes, int n_in,
                              void* d_out, int out_size, void* d_ws, size_t ws_size,
                              hipStream_t stream)
{
    const float* G      = (const float*)d_in[0];
    const float* x_seq  = (const float*)d_in[1];
    const float* init_h = (const float*)d_in[2];
    const float* init_c = (const float*)d_in[3];
    const float* x_meta = (const float*)d_in[4];
    const float* lw1_0 = (const float*)d_in[5],  *lb1_0 = (const float*)d_in[6];
    const float* lw2_0 = (const float*)d_in[7],  *lb2_0 = (const float*)d_in[8];
    const float* bw1_0 = (const float*)d_in[9],  *bb1_0 = (const float*)d_in[10];
    const float* bw2_0 = (const float*)d_in[11], *bb2_0 = (const float*)d_in[12];
    const float* lw1_1 = (const float*)d_in[13], *lb1_1 = (const float*)d_in[14];
    const float* lw2_1 = (const float*)d_in[15], *lb2_1 = (const float*)d_in[16];
    const float* bw1_1 = (const float*)d_in[17], *bb1_1 = (const float*)d_in[18];
    const float* bw2_1 = (const float*)d_in[19], *bb2_1 = (const float*)d_in[20];

    if (ws_size < WS_NEEDED) return;

    char* ws = (char*)d_ws;
    bf16*  Gbf   = (bf16*) (ws + OFF_GBF);
    bf16*  XrT0  = (bf16*) (ws + OFF_XRT0);
    bf16*  XrT1  = (bf16*) (ws + OFF_XRT1);
    bf16*  Xs0T  = (bf16*) (ws + OFF_XS0T);
    bf16*  hs0T  = (bf16*) (ws + OFF_HS0T);
    bf16*  S0x   = (bf16*) (ws + OFF_S0X);
    bf16*  S1s   = (bf16*) (ws + OFF_S1S);
    bf16*  W0sw  = (bf16*) (ws + OFF_W0SW);
    bf16*  W1sw  = (bf16*) (ws + OFF_W1SW);
    float* bias0 = (float*)(ws + OFF_BIAS0);
    float* bias1 = (float*)(ws + OFF_BIAS1);
    float* c0    = (float*)(ws + OFF_C0);
    float* c1    = (float*)(ws + OFF_C1);
    float* out   = (float*)d_out;

    prep_kernel<<<4096, 256, 0, stream>>>(G, x_seq, init_h, init_c,
                                          Gbf, XrT0, XrT1, Xs0T, c0, c1);
    metaw_kernel<<<584, 256, 0, stream>>>(x_meta,
        lw1_0, lb1_0, lw2_0, lb2_0, bw1_0, bb1_0, bw2_0, bb2_0,
        lw1_1, lb1_1, lw2_1, lb2_1, bw1_1, bb1_1, bw2_1, bb2_1,
        W0sw, W1sw, bias0, bias1);

    gemm_tile<2><<<48, 256, 0, stream>>>((const short*)Gbf, (const short*)Xs0T, S0x);

    for (int t = 0; t < 8; t++)
        step_fused<0><<<256, 256, 0, stream>>>((const short*)Gbf, (const short*)S0x,
            (const short*)W0sw, bias0, c0, XrT0, hs0T, out, t);

    gemm_tile<1><<<768, 256, 0, stream>>>((const short*)Gbf, (const short*)hs0T, S1s);

    for (int t = 0; t < 8; t++)
        step_fused<1><<<256, 256, 0, stream>>>((const short*)Gbf, (const short*)S1s,
            (const short*)W1sw, bias1, c1, XrT1, nullptr, out, t);
}